// Round 7
// baseline (598.159 us; speedup 1.0000x reference)
//
#include <hip/hip_runtime.h>
#include <stdint.h>

#define B_ 2
#define NX_ 2048
#define NLQ_ 64
#define T_ 2112
#define DIN_ 768
#define DOUT_ 768
#define NH_ 12
#define HD_ 64

#define QSZ_ ((size_t)3244032)   // B*NH*T*HD elements
#define HALF_U 53526528u         // NH*T*T (per-batch flat count)
#define SCALE_ ((float)(4460544.0 / (4194304.0 * 0.9 + 266240.0 * 0.8)))
// pre-shifted integer dropout thresholds: keep  <=>  (y.x^y.y) < thr<<9
// 0.9f = 15099494/2^24 -> thr 7549747 ; 0.8f = 13421773/2^24 -> thr 6710887
#define KXS_ 3865470464u
#define KLQS_ 3435974144u

typedef __attribute__((ext_vector_type(8))) short bf16x8;
typedef __attribute__((ext_vector_type(4))) float f32x4;
typedef unsigned int uint32;

__device__ __forceinline__ uint32 rotl_(uint32 x, uint32 r) {
  return (x << r) | (x >> (32u - r));
}

// Threefry-2x32, 20 rounds, key=(0,42); jax partitionable 32-bit: out = y.x ^ y.y
__device__ __forceinline__ uint2 threefry_(uint32 x0, uint32 x1) {
  const uint32 ks0 = 0u, ks1 = 42u;
  const uint32 ks2 = 0x1BD11BDAu ^ ks0 ^ ks1;
  x0 += ks0; x1 += ks1;
#define TFR_(r) { x0 += x1; x1 = rotl_(x1, (r)); x1 ^= x0; }
  TFR_(13) TFR_(15) TFR_(26) TFR_(6)
  x0 += ks1; x1 += ks2 + 1u;
  TFR_(17) TFR_(29) TFR_(16) TFR_(24)
  x0 += ks2; x1 += ks0 + 2u;
  TFR_(13) TFR_(15) TFR_(26) TFR_(6)
  x0 += ks0; x1 += ks1 + 3u;
  TFR_(17) TFR_(29) TFR_(16) TFR_(24)
  x0 += ks1; x1 += ks2 + 4u;
  TFR_(13) TFR_(15) TFR_(26) TFR_(6)
  x0 += ks2; x1 += ks0 + 5u;
#undef TFR_
  return make_uint2(x0, x1);
}

__device__ __forceinline__ unsigned short f2b_(float f) {  // f32 -> bf16 RNE
  const uint32 u = __float_as_uint(f);
  return (unsigned short)((u + 0x7FFFu + ((u >> 16) & 1u)) >> 16);
}
__device__ __forceinline__ uint32 pack2_(float lo, float hi) {
  return (uint32)f2b_(lo) | ((uint32)f2b_(hi) << 16);
}

// ---------- xconv: [x; lq] f32 -> Xb bf16 [B*T][768] ----------
__global__ __launch_bounds__(256) void xconv_kernel(
    const float* __restrict__ xg, const float* __restrict__ lqg,
    unsigned short* __restrict__ Xb) {
  const uint32 f = (blockIdx.x * 256u + threadIdx.x) * 8u;
  const uint32 m = f / 768u;
  const uint32 col = f - m * 768u;
  const uint32 bb = (m >= (uint32)T_) ? 1u : 0u;
  const uint32 tt = m - bb * (uint32)T_;
  const float* src = (tt < NX_) ? (xg + ((size_t)bb * NX_ + tt) * DIN_ + col)
                                : (lqg + ((size_t)bb * NLQ_ + (tt - NX_)) * DIN_ + col);
  const float4 a = *(const float4*)(src);
  const float4 b = *(const float4*)(src + 4);
  uint4 o;
  o.x = pack2_(a.x, a.y); o.y = pack2_(a.z, a.w);
  o.z = pack2_(b.x, b.y); o.w = pack2_(b.z, b.w);
  *(uint4*)(Xb + f) = o;
}

// ---------- prep: Wt[mat][n][k] bf16 = transpose(W[k][n]) for q,k,v,o ----------
__global__ __launch_bounds__(256) void prep_kernel(
    const float* __restrict__ Wq, const float* __restrict__ Wk,
    const float* __restrict__ Wv, const float* __restrict__ Wo,
    unsigned short* __restrict__ Wt) {
  __shared__ float Tf[64][65];
  const int tid = threadIdx.x;
  const int k0 = blockIdx.x << 6;
  const int n0 = blockIdx.y << 6;
  const int mat = blockIdx.z;
  const float* Wm = (mat == 0) ? Wq : (mat == 1) ? Wk : (mat == 2) ? Wv : Wo;
  const int r = tid >> 2;
  const int cch = (tid & 3) << 4;
  const float* src = Wm + (size_t)(k0 + r) * DOUT_ + n0 + cch;
#pragma unroll
  for (int j = 0; j < 4; ++j) {
    const float4 v = *(const float4*)(src + 4 * j);
    Tf[r][cch + 4 * j + 0] = v.x; Tf[r][cch + 4 * j + 1] = v.y;
    Tf[r][cch + 4 * j + 2] = v.z; Tf[r][cch + 4 * j + 3] = v.w;
  }
  __syncthreads();
  float f[16];
#pragma unroll
  for (int j = 0; j < 16; ++j) f[j] = Tf[cch + j][r];
  uint4 o0, o1;
  o0.x = pack2_(f[0], f[1]);  o0.y = pack2_(f[2], f[3]);
  o0.z = pack2_(f[4], f[5]);  o0.w = pack2_(f[6], f[7]);
  o1.x = pack2_(f[8], f[9]);  o1.y = pack2_(f[10], f[11]);
  o1.z = pack2_(f[12], f[13]); o1.w = pack2_(f[14], f[15]);
  unsigned short* dst = Wt + ((size_t)mat * DOUT_ + n0 + r) * DIN_ + k0 + cch;
  *(uint4*)dst = o0;
  *(uint4*)(dst + 8) = o1;
}

// ---------- qkv: one block = (64 m-rows, head h) -> Q|K|V (N=192) + mask phase ----------
__global__ __launch_bounds__(256) void qkv_kernel(
    const unsigned short* __restrict__ Xb, const unsigned short* __restrict__ Wt,
    unsigned short* __restrict__ Qh, unsigned short* __restrict__ Kh,
    unsigned short* __restrict__ Vth, uint32* __restrict__ Mask) {
  __shared__ unsigned short AsB[4096];    // [64 m][64 k] swizzled
  __shared__ unsigned short BsB[12288];   // [192 n][64 k] swizzled (q0-63,k64-127,v128-191)
  const int tid = threadIdx.x;
  const int w = tid >> 6;
  const int lane = tid & 63;
  const int c = lane & 15;
  const int g = lane >> 4;
  const int m0 = blockIdx.x << 6;
  const int h  = blockIdx.y;

  const int srow = tid >> 2;          // 0..63
  const int seg  = (tid & 3) << 5;    // byte offset {0,32,64,96} within 128B row-tile
  const int swzR = ((srow & 7) << 4);
  const int swzF = (c & 7) << 4;

  f32x4 acc[12];
#pragma unroll
  for (int nt = 0; nt < 12; ++nt) acc[nt] = (f32x4){0.f, 0.f, 0.f, 0.f};

  const unsigned short* arow = Xb + (size_t)(m0 + srow) * DIN_;

  for (int k0 = 0; k0 < DIN_; k0 += 64) {
    const uint4 a0 = *(const uint4*)(arow + k0 + (seg >> 1));
    const uint4 a1 = *(const uint4*)(arow + k0 + (seg >> 1) + 8);
    uint4 b0[3], b1[3];
#pragma unroll
    for (int ii = 0; ii < 3; ++ii) {
      const int n = srow + (ii << 6);
      const unsigned short* brow =
          Wt + ((size_t)(n >> 6) * DOUT_ + h * HD_ + (n & 63)) * DIN_ + k0 + (seg >> 1);
      b0[ii] = *(const uint4*)(brow);
      b1[ii] = *(const uint4*)(brow + 8);
    }
    __syncthreads();
    *(uint4*)((char*)AsB + srow * 128 + (seg ^ swzR)) = a0;
    *(uint4*)((char*)AsB + srow * 128 + ((seg + 16) ^ swzR)) = a1;
#pragma unroll
    for (int ii = 0; ii < 3; ++ii) {
      const int n = srow + (ii << 6);
      *(uint4*)((char*)BsB + n * 128 + (seg ^ swzR)) = b0[ii];
      *(uint4*)((char*)BsB + n * 128 + ((seg + 16) ^ swzR)) = b1[ii];
    }
    __syncthreads();
#pragma unroll
    for (int s = 0; s < 2; ++s) {
      const int off = ((s << 6) | (g << 4)) ^ swzF;
      const bf16x8 af = *(const bf16x8*)((const char*)AsB + (16 * w + c) * 128 + off);
#pragma unroll
      for (int nt = 0; nt < 12; ++nt) {
        const bf16x8 bf = *(const bf16x8*)((const char*)BsB + (nt * 16 + c) * 128 + off);
        acc[nt] = __builtin_amdgcn_mfma_f32_16x16x32_bf16(af, bf, acc[nt], 0, 0, 0);
      }
    }
    __syncthreads();
  }

  const int bb2 = m0 / T_;
  const int tb = m0 - bb2 * T_;
  const size_t rowBase = (size_t)(bb2 * NH_ + h) * T_ + tb;
#pragma unroll
  for (int nt = 0; nt < 4; ++nt)
#pragma unroll
    for (int i = 0; i < 4; ++i)
      Qh[(rowBase + 16 * w + 4 * g + i) * HD_ + nt * 16 + c] = f2b_(acc[nt][i] * 0.125f);
#pragma unroll
  for (int nt = 4; nt < 8; ++nt)
#pragma unroll
    for (int i = 0; i < 4; ++i)
      Kh[(rowBase + 16 * w + 4 * g + i) * HD_ + (nt - 4) * 16 + c] = f2b_(acc[nt][i]);
  // V: transpose 64m x 64hd through AsB
#pragma unroll
  for (int nt = 8; nt < 12; ++nt) {
    const int hd = (nt - 8) * 16 + c;
#pragma unroll
    for (int i = 0; i < 4; ++i) {
      const int col2 = (16 * w + 4 * g + i) * 2;
      *(unsigned short*)((char*)AsB + hd * 128 + (col2 ^ swzF)) = f2b_(acc[nt][i]);
    }
  }
  __syncthreads();
  {
    const int hd = tid >> 2;
    const int ch = (tid & 3) << 5;
    const uint4 v0 = *(const uint4*)((const char*)AsB + hd * 128 + (ch ^ ((hd & 7) << 4)));
    const uint4 v1 = *(const uint4*)((const char*)AsB + hd * 128 + ((ch + 16) ^ ((hd & 7) << 4)));
    unsigned short* dst = Vth + ((size_t)(bb2 * NH_ + h) * HD_ + hd) * T_ + tb + (ch >> 1);
    *(uint4*)dst = v0;
    *(uint4*)(dst + 8) = v1;
  }

  // ---- threefry dropout-mask phase: ballot-packed, 4224 words/block ----
  const uint32 wvbeg = (uint32)(blockIdx.y * 66 + blockIdx.x) * 4224u + (uint32)w * 1056u;
  for (uint32 wI = wvbeg; wI < wvbeg + 1056u; wI += 4u) {
    const uint32 b0 = wI * 32u;
    const uint32 g0 = b0 + (uint32)lane;
    const uint32 g1 = g0 + 64u;
    uint32 thrS0, thrS1;
    {
      const uint32 row0 = b0 / 2112u;
      const uint32 cb0 = b0 - row0 * 2112u;
      thrS0 = ((row0 % 2112u) < 2048u && cb0 < 2048u) ? KXS_ : KLQS_;
      const uint32 b1 = b0 + 64u;
      const uint32 row1 = b1 / 2112u;
      const uint32 cb1 = b1 - row1 * 2112u;
      thrS1 = ((row1 % 2112u) < 2048u && cb1 < 2048u) ? KXS_ : KLQS_;
    }
    const uint2 ya = threefry_(0u, g0);
    const uint2 yb = threefry_(0u, g1);
    const unsigned long long balA = __ballot((ya.x ^ ya.y) < thrS0);
    const unsigned long long balB = __ballot((yb.x ^ yb.y) < thrS1);
    if (lane == 0) {
      uint4 st;
      st.x = (uint32)balA; st.y = (uint32)(balA >> 32);
      st.z = (uint32)balB; st.w = (uint32)(balB >> 32);
      *(uint4*)(Mask + wI) = st;
    }
  }
}

// ---------- MFMA flash attention (64 q-rows, 4 waves), reads precomputed mask ----------
__global__ __launch_bounds__(256) void attn_kernel(
    const unsigned short* __restrict__ Qh, const unsigned short* __restrict__ Kh,
    const unsigned short* __restrict__ Vth, const uint32* __restrict__ Mask,
    float* __restrict__ ctx) {
  __shared__ unsigned short KsU[4096];
  __shared__ unsigned short VsU[4096];
  __shared__ unsigned short PsU[4 * 1152];
  const int tid = threadIdx.x;
  const int w = tid >> 6;
  const int lane = tid & 63;
  const int c = lane & 15;
  const int g = lane >> 4;
  const int q0 = blockIdx.x << 6;
  const int h = blockIdx.y;
  const int b = blockIdx.z;
  const size_t hbT = (size_t)(b * NH_ + h) * T_;
  const size_t vbase = (size_t)(b * NH_ + h) * HD_;

  bf16x8 aq0, aq1;
  {
    const unsigned short* qrow = Qh + (hbT + q0 + 16 * w + c) * HD_ + (g << 3);
    aq0 = *(const bf16x8*)(qrow);
    aq1 = *(const bf16x8*)(qrow + 32);
  }
  f32x4 ca0 = {0.f, 0.f, 0.f, 0.f}, ca1 = ca0, ca2 = ca0, ca3 = ca0;
  float lacc[4] = {0.f, 0.f, 0.f, 0.f};
  uint32 wb[4];
#pragma unroll
  for (int i = 0; i < 4; ++i)
    wb[i] = ((uint32)b * HALF_U +
             (uint32)(h * T_ + q0 + 16 * w + 4 * g + i) * (uint32)T_) >> 5;

  const int psE = w * 1152;
  const int psB = w * 2304;
  const int swz = (c & 7) << 4;

  for (int kt = 0; kt < T_; kt += 64) {
#pragma unroll
    for (int ii = 0; ii < 2; ++ii) {
      const int seg = tid + (ii << 8);
      const int srow = seg >> 3;
      const int sc = (seg & 7) << 3;
      const uint4 kv4 = *(const uint4*)(Kh + (hbT + kt + srow) * HD_ + sc);
      *(uint4*)((char*)KsU + srow * 128 + ((sc * 2) ^ ((srow & 7) << 4))) = kv4;
      const uint4 vv4 = *(const uint4*)(Vth + (vbase + srow) * T_ + kt + sc);
      *(uint4*)((char*)VsU + srow * 128 + ((sc * 2) ^ ((srow & 7) << 4))) = vv4;
    }
    __syncthreads();

    f32x4 sa0 = {0.f, 0.f, 0.f, 0.f}, sa1 = sa0, sa2 = sa0, sa3 = sa0;
#pragma unroll
    for (int s = 0; s < 2; ++s) {
      const int off = ((s << 6) | (g << 4)) ^ swz;
      const bf16x8 bk0 = *(const bf16x8*)((const char*)KsU + (c) * 128 + off);
      const bf16x8 bk1 = *(const bf16x8*)((const char*)KsU + (c + 16) * 128 + off);
      const bf16x8 bk2 = *(const bf16x8*)((const char*)KsU + (c + 32) * 128 + off);
      const bf16x8 bk3 = *(const bf16x8*)((const char*)KsU + (c + 48) * 128 + off);
      const bf16x8 aqs = s ? aq1 : aq0;
      sa0 = __builtin_amdgcn_mfma_f32_16x16x32_bf16(aqs, bk0, sa0, 0, 0, 0);
      sa1 = __builtin_amdgcn_mfma_f32_16x16x32_bf16(aqs, bk1, sa1, 0, 0, 0);
      sa2 = __builtin_amdgcn_mfma_f32_16x16x32_bf16(aqs, bk2, sa2, 0, 0, 0);
      sa3 = __builtin_amdgcn_mfma_f32_16x16x32_bf16(aqs, bk3, sa3, 0, 0, 0);
    }

    const uint32 ktw = (uint32)(kt >> 5);
#pragma unroll
    for (int n = 0; n < 4; ++n) {
      const f32x4 sv = (n == 0) ? sa0 : (n == 1) ? sa1 : (n == 2) ? sa2 : sa3;
      const int sh = ((n & 1) << 4) + c;
      const uint32 wOff = ktw + (n >> 1);
#pragma unroll
      for (int i = 0; i < 4; ++i) {
        const float pe = __expf(sv[i]);
        lacc[i] += pe;
        const uint32 word = Mask[wb[i] + wOff];
        PsU[psE + (4 * g + i) * 72 + 16 * n + c] =
            ((word >> sh) & 1u) ? f2b_(pe) : (unsigned short)0;
      }
    }
    __syncthreads();

    const bf16x8 ap0 = *(const bf16x8*)((const char*)PsU + psB + c * 144 + (g << 4));
    const bf16x8 ap1 = *(const bf16x8*)((const char*)PsU + psB + c * 144 + 64 + (g << 4));
#pragma unroll
    for (int s = 0; s < 2; ++s) {
      const int off = ((s << 6) | (g << 4)) ^ swz;
      const bf16x8 bv0 = *(const bf16x8*)((const char*)VsU + (c) * 128 + off);
      const bf16x8 bv1 = *(const bf16x8*)((const char*)VsU + (c + 16) * 128 + off);
      const bf16x8 bv2 = *(const bf16x8*)((const char*)VsU + (c + 32) * 128 + off);
      const bf16x8 bv3 = *(const bf16x8*)((const char*)VsU + (c + 48) * 128 + off);
      const bf16x8 aps = s ? ap1 : ap0;
      ca0 = __builtin_amdgcn_mfma_f32_16x16x32_bf16(aps, bv0, ca0, 0, 0, 0);
      ca1 = __builtin_amdgcn_mfma_f32_16x16x32_bf16(aps, bv1, ca1, 0, 0, 0);
      ca2 = __builtin_amdgcn_mfma_f32_16x16x32_bf16(aps, bv2, ca2, 0, 0, 0);
      ca3 = __builtin_amdgcn_mfma_f32_16x16x32_bf16(aps, bv3, ca3, 0, 0, 0);
    }
    __syncthreads();
  }

#pragma unroll
  for (int i = 0; i < 4; ++i) {
    float li = lacc[i];
    li += __shfl_xor(li, 1);
    li += __shfl_xor(li, 2);
    li += __shfl_xor(li, 4);
    li += __shfl_xor(li, 8);
    const float inv = SCALE_ / li;
    float* dst = ctx + (size_t)(b * T_ + q0 + 16 * w + 4 * g + i) * DOUT_ + (h << 6) + c;
    dst[0]  = ca0[i] * inv;
    dst[16] = ca1[i] * inv;
    dst[32] = ca2[i] * inv;
    dst[48] = ca3[i] * inv;
  }
}

// ---------- oproj: bf16 MFMA GEMM + bias ----------
__global__ __launch_bounds__(256) void oproj_kernel(
    const float* __restrict__ ctxm, const unsigned short* __restrict__ Wt,
    const float* __restrict__ bo, float* __restrict__ out) {
  __shared__ unsigned short AsB[4096];
  __shared__ unsigned short BsB[4096];
  const int tid = threadIdx.x;
  const int w = tid >> 6;
  const int lane = tid & 63;
  const int c = lane & 15;
  const int g = lane >> 4;
  const int m0 = blockIdx.x << 6;
  const int n0 = blockIdx.y << 6;
  const int ar = tid >> 2;
  const int kpart = (tid & 3) << 4;
  const float* arow = ctxm + (size_t)(m0 + ar) * DIN_;
  const unsigned short* brow = Wt + ((size_t)3 * DOUT_ + n0 + ar) * DIN_;
  const int wrA = ar * 128;
  const int swzS = (ar & 7) << 4;
  const int swzF = (c & 7) << 4;

  f32x4 ac0 = {0.f, 0.f, 0.f, 0.f}, ac1 = ac0, ac2 = ac0, ac3 = ac0;
  for (int k0 = 0; k0 < DIN_; k0 += 64) {
    const float4 a0 = *(const float4*)(arow + k0 + kpart);
    const float4 a1 = *(const float4*)(arow + k0 + kpart + 4);
    const float4 a2 = *(const float4*)(arow + k0 + kpart + 8);
    const float4 a3 = *(const float4*)(arow + k0 + kpart + 12);
    const uint4 b01 = *(const uint4*)(brow + k0 + kpart);
    const uint4 b23 = *(const uint4*)(brow + k0 + kpart + 8);
    uint4 pa0, pa1;
    pa0.x = pack2_(a0.x, a0.y); pa0.y = pack2_(a0.z, a0.w);
    pa0.z = pack2_(a1.x, a1.y); pa0.w = pack2_(a1.z, a1.w);
    pa1.x = pack2_(a2.x, a2.y); pa1.y = pack2_(a2.z, a2.w);
    pa1.z = pack2_(a3.x, a3.y); pa1.w = pack2_(a3.z, a3.w);
    __syncthreads();
    *(uint4*)((char*)AsB + wrA + ((kpart * 2) ^ swzS)) = pa0;
    *(uint4*)((char*)AsB + wrA + ((kpart * 2 + 16) ^ swzS)) = pa1;
    *(uint4*)((char*)BsB + wrA + ((kpart * 2) ^ swzS)) = b01;
    *(uint4*)((char*)BsB + wrA + ((kpart * 2 + 16) ^ swzS)) = b23;
    __syncthreads();
#pragma unroll
    for (int s = 0; s < 2; ++s) {
      const int off = ((s << 6) | (g << 4)) ^ swzF;
      const bf16x8 af = *(const bf16x8*)((const char*)AsB + (16 * w + c) * 128 + off);
      const bf16x8 b0 = *(const bf16x8*)((const char*)BsB + (c) * 128 + off);
      const bf16x8 b1 = *(const bf16x8*)((const char*)BsB + (c + 16) * 128 + off);
      const bf16x8 b2 = *(const bf16x8*)((const char*)BsB + (c + 32) * 128 + off);
      const bf16x8 b3 = *(const bf16x8*)((const char*)BsB + (c + 48) * 128 + off);
      ac0 = __builtin_amdgcn_mfma_f32_16x16x32_bf16(af, b0, ac0, 0, 0, 0);
      ac1 = __builtin_amdgcn_mfma_f32_16x16x32_bf16(af, b1, ac1, 0, 0, 0);
      ac2 = __builtin_amdgcn_mfma_f32_16x16x32_bf16(af, b2, ac2, 0, 0, 0);
      ac3 = __builtin_amdgcn_mfma_f32_16x16x32_bf16(af, b3, ac3, 0, 0, 0);
    }
  }
  const float bi0 = bo[n0 + c];
  const float bi1 = bo[n0 + 16 + c];
  const float bi2 = bo[n0 + 32 + c];
  const float bi3 = bo[n0 + 48 + c];
#pragma unroll
  for (int i = 0; i < 4; ++i) {
    float* dst = out + (size_t)(m0 + 16 * w + 4 * g + i) * DOUT_ + n0 + c;
    dst[0]  = ac0[i] + bi0;
    dst[16] = ac1[i] + bi1;
    dst[32] = ac2[i] + bi2;
    dst[48] = ac3[i] + bi3;
  }
}

extern "C" void kernel_launch(void* const* d_in, const int* in_sizes, int n_in,
                              void* d_out, int out_size, void* d_ws, size_t ws_size,
                              hipStream_t stream) {
  (void)in_sizes; (void)n_in; (void)out_size; (void)ws_size;
  const float* x  = (const float*)d_in[0];
  const float* lq = (const float*)d_in[1];
  const float* Wq = (const float*)d_in[2];
  const float* Wk = (const float*)d_in[3];
  const float* Wv = (const float*)d_in[4];
  const float* Wo = (const float*)d_in[5];
  const float* bo = (const float*)d_in[6];
  unsigned short* Qh  = (unsigned short*)d_ws;
  unsigned short* Kh  = Qh + QSZ_;
  unsigned short* Vth = Kh + QSZ_;
  float* Cb = (float*)(Vth + QSZ_);                  // 19.46 MB off (12.98 MB)
  unsigned short* Xb = (unsigned short*)Cb;          // aliases Cb: dead before attn
  unsigned short* Wt = (unsigned short*)(Cb + QSZ_); // 32.44 MB off (4.72 MB)
  uint32* Mask = (uint32*)((char*)d_ws + 37158912);  // 13.38 MB -> ends 50.5 MB
  xconv_kernel<<<dim3(1584), dim3(256), 0, stream>>>(x, lq, Xb);
  prep_kernel<<<dim3(12, 12, 4), dim3(256), 0, stream>>>(Wq, Wk, Wv, Wo, Wt);
  qkv_kernel<<<dim3(66, 12), dim3(256), 0, stream>>>(Xb, Wt, Qh, Kh, Vth, Mask);
  attn_kernel<<<dim3(33, NH_, B_), dim3(256), 0, stream>>>(Qh, Kh, Vth, Mask, Cb);
  oproj_kernel<<<dim3(66, 12), dim3(256), 0, stream>>>(Cb, Wt, bo, (float*)d_out);
}

// Round 8
// 480.810 us; speedup vs baseline: 1.2441x; 1.2441x over previous
//
#include <hip/hip_runtime.h>
#include <stdint.h>

#define B_ 2
#define NX_ 2048
#define NLQ_ 64
#define T_ 2112
#define DIN_ 768
#define DOUT_ 768
#define NH_ 12
#define HD_ 64

#define QSZ_ ((size_t)3244032)   // B*NH*T*HD elements
#define HALF_U 53526528u         // NH*T*T (per-batch flat count)
#define SCALE_ ((float)(4460544.0 / (4194304.0 * 0.9 + 266240.0 * 0.8)))
// pre-shifted integer dropout thresholds: keep  <=>  (y.x^y.y) < thr<<9
#define KXS_ 3865470464u
#define KLQS_ 3435974144u

typedef __attribute__((ext_vector_type(8))) short bf16x8;
typedef __attribute__((ext_vector_type(4))) float f32x4;
typedef unsigned int uint32;

__device__ __forceinline__ uint32 rotl_(uint32 x, uint32 r) {
  return (x << r) | (x >> (32u - r));
}

// Threefry-2x32, 20 rounds, key=(0,42); jax partitionable 32-bit: out = y.x ^ y.y
__device__ __forceinline__ uint2 threefry_(uint32 x0, uint32 x1) {
  const uint32 ks0 = 0u, ks1 = 42u;
  const uint32 ks2 = 0x1BD11BDAu ^ ks0 ^ ks1;
  x0 += ks0; x1 += ks1;
#define TFR_(r) { x0 += x1; x1 = rotl_(x1, (r)); x1 ^= x0; }
  TFR_(13) TFR_(15) TFR_(26) TFR_(6)
  x0 += ks1; x1 += ks2 + 1u;
  TFR_(17) TFR_(29) TFR_(16) TFR_(24)
  x0 += ks2; x1 += ks0 + 2u;
  TFR_(13) TFR_(15) TFR_(26) TFR_(6)
  x0 += ks0; x1 += ks1 + 3u;
  TFR_(17) TFR_(29) TFR_(16) TFR_(24)
  x0 += ks1; x1 += ks2 + 4u;
  TFR_(13) TFR_(15) TFR_(26) TFR_(6)
  x0 += ks2; x1 += ks0 + 5u;
#undef TFR_
  return make_uint2(x0, x1);
}

__device__ __forceinline__ unsigned short f2b_(float f) {  // f32 -> bf16 RNE
  const uint32 u = __float_as_uint(f);
  return (unsigned short)((u + 0x7FFFu + ((u >> 16) & 1u)) >> 16);
}
__device__ __forceinline__ uint32 pack2_(float lo, float hi) {
  return (uint32)f2b_(lo) | ((uint32)f2b_(hi) << 16);
}

// ---------- xconv: [x; lq] f32 -> Xb bf16 [B*T][768] ----------
__global__ __launch_bounds__(256) void xconv_kernel(
    const float* __restrict__ xg, const float* __restrict__ lqg,
    unsigned short* __restrict__ Xb) {
  const uint32 f = (blockIdx.x * 256u + threadIdx.x) * 8u;
  const uint32 m = f / 768u;
  const uint32 col = f - m * 768u;
  const uint32 bb = (m >= (uint32)T_) ? 1u : 0u;
  const uint32 tt = m - bb * (uint32)T_;
  const float* src = (tt < NX_) ? (xg + ((size_t)bb * NX_ + tt) * DIN_ + col)
                                : (lqg + ((size_t)bb * NLQ_ + (tt - NX_)) * DIN_ + col);
  const float4 a = *(const float4*)(src);
  const float4 b = *(const float4*)(src + 4);
  uint4 o;
  o.x = pack2_(a.x, a.y); o.y = pack2_(a.z, a.w);
  o.z = pack2_(b.x, b.y); o.w = pack2_(b.z, b.w);
  *(uint4*)(Xb + f) = o;
}

// ---------- prep: Wt[mat][n][k] bf16 = transpose(W[k][n]) for q,k,v,o ----------
__global__ __launch_bounds__(256) void prep_kernel(
    const float* __restrict__ Wq, const float* __restrict__ Wk,
    const float* __restrict__ Wv, const float* __restrict__ Wo,
    unsigned short* __restrict__ Wt) {
  __shared__ float Tf[64][65];
  const int tid = threadIdx.x;
  const int k0 = blockIdx.x << 6;
  const int n0 = blockIdx.y << 6;
  const int mat = blockIdx.z;
  const float* Wm = (mat == 0) ? Wq : (mat == 1) ? Wk : (mat == 2) ? Wv : Wo;
  const int r = tid >> 2;
  const int cch = (tid & 3) << 4;
  const float* src = Wm + (size_t)(k0 + r) * DOUT_ + n0 + cch;
#pragma unroll
  for (int j = 0; j < 4; ++j) {
    const float4 v = *(const float4*)(src + 4 * j);
    Tf[r][cch + 4 * j + 0] = v.x; Tf[r][cch + 4 * j + 1] = v.y;
    Tf[r][cch + 4 * j + 2] = v.z; Tf[r][cch + 4 * j + 3] = v.w;
  }
  __syncthreads();
  float f[16];
#pragma unroll
  for (int j = 0; j < 16; ++j) f[j] = Tf[cch + j][r];
  uint4 o0, o1;
  o0.x = pack2_(f[0], f[1]);  o0.y = pack2_(f[2], f[3]);
  o0.z = pack2_(f[4], f[5]);  o0.w = pack2_(f[6], f[7]);
  o1.x = pack2_(f[8], f[9]);  o1.y = pack2_(f[10], f[11]);
  o1.z = pack2_(f[12], f[13]); o1.w = pack2_(f[14], f[15]);
  unsigned short* dst = Wt + ((size_t)mat * DOUT_ + n0 + r) * DIN_ + k0 + cch;
  *(uint4*)dst = o0;
  *(uint4*)(dst + 8) = o1;
}

// ---------- qkv: bf16 MFMA GEMM (Q*0.125, K, V-transposed) + threefry mask phase ----------
// grid (36, 66): x = wsel*12+h (A-tile reuse: 36 consecutive blocks share one m-tile)
__global__ __launch_bounds__(256) void qkv_kernel(
    const unsigned short* __restrict__ Xb, const unsigned short* __restrict__ Wt,
    unsigned short* __restrict__ Qh, unsigned short* __restrict__ Kh,
    unsigned short* __restrict__ Vth, uint32* __restrict__ Mask) {
  __shared__ unsigned short AsB[4096];   // [64 m][64 k] bf16, XOR-swizzled rows
  __shared__ unsigned short BsB[4096];   // [64 n][64 k] bf16 (=W^T tile)
  const int tid = threadIdx.x;
  const int w = tid >> 6;
  const int lane = tid & 63;
  const int c = lane & 15;
  const int g = lane >> 4;
  const int wsel = blockIdx.x / NH_;
  const int h = blockIdx.x % NH_;
  const int m0 = blockIdx.y << 6;

  const int ar = tid >> 2;
  const int kpart = (tid & 3) << 4;
  const unsigned short* arow = Xb + (size_t)(m0 + ar) * DIN_;
  const unsigned short* brow = Wt + ((size_t)wsel * DOUT_ + h * HD_ + ar) * DIN_;
  const int wrA = ar * 128;
  const int swzS = (ar & 7) << 4;
  const int swzF = (c & 7) << 4;

  f32x4 ac0 = {0.f, 0.f, 0.f, 0.f}, ac1 = ac0, ac2 = ac0, ac3 = ac0;

  for (int k0 = 0; k0 < DIN_; k0 += 64) {
    const uint4 a01 = *(const uint4*)(arow + k0 + kpart);
    const uint4 a23 = *(const uint4*)(arow + k0 + kpart + 8);
    const uint4 b01 = *(const uint4*)(brow + k0 + kpart);
    const uint4 b23 = *(const uint4*)(brow + k0 + kpart + 8);
    __syncthreads();
    *(uint4*)((char*)AsB + wrA + ((kpart * 2) ^ swzS)) = a01;
    *(uint4*)((char*)AsB + wrA + ((kpart * 2 + 16) ^ swzS)) = a23;
    *(uint4*)((char*)BsB + wrA + ((kpart * 2) ^ swzS)) = b01;
    *(uint4*)((char*)BsB + wrA + ((kpart * 2 + 16) ^ swzS)) = b23;
    __syncthreads();
#pragma unroll
    for (int s = 0; s < 2; ++s) {
      const int off = ((s << 6) | (g << 4)) ^ swzF;
      const bf16x8 af = *(const bf16x8*)((const char*)AsB + (16 * w + c) * 128 + off);
      const bf16x8 b0 = *(const bf16x8*)((const char*)BsB + (c) * 128 + off);
      const bf16x8 b1 = *(const bf16x8*)((const char*)BsB + (c + 16) * 128 + off);
      const bf16x8 b2 = *(const bf16x8*)((const char*)BsB + (c + 32) * 128 + off);
      const bf16x8 b3 = *(const bf16x8*)((const char*)BsB + (c + 48) * 128 + off);
      ac0 = __builtin_amdgcn_mfma_f32_16x16x32_bf16(af, b0, ac0, 0, 0, 0);
      ac1 = __builtin_amdgcn_mfma_f32_16x16x32_bf16(af, b1, ac1, 0, 0, 0);
      ac2 = __builtin_amdgcn_mfma_f32_16x16x32_bf16(af, b2, ac2, 0, 0, 0);
      ac3 = __builtin_amdgcn_mfma_f32_16x16x32_bf16(af, b3, ac3, 0, 0, 0);
    }
  }

  const int bb2 = m0 / T_;
  const int tb = m0 - bb2 * T_;
  const size_t rowBase = (size_t)(bb2 * NH_ + h) * T_;
  if (wsel == 0) {
#pragma unroll
    for (int i = 0; i < 4; ++i) {
      const size_t rr = (rowBase + tb + 16 * w + 4 * g + i) * HD_ + c;
      Qh[rr +  0] = f2b_(ac0[i] * 0.125f);
      Qh[rr + 16] = f2b_(ac1[i] * 0.125f);
      Qh[rr + 32] = f2b_(ac2[i] * 0.125f);
      Qh[rr + 48] = f2b_(ac3[i] * 0.125f);
    }
  } else if (wsel == 1) {
#pragma unroll
    for (int i = 0; i < 4; ++i) {
      const size_t rr = (rowBase + tb + 16 * w + 4 * g + i) * HD_ + c;
      Kh[rr +  0] = f2b_(ac0[i]);
      Kh[rr + 16] = f2b_(ac1[i]);
      Kh[rr + 32] = f2b_(ac2[i]);
      Kh[rr + 48] = f2b_(ac3[i]);
    }
  } else {
    __syncthreads();   // all frag reads done; reuse AsB as transpose buffer
#pragma unroll
    for (int i = 0; i < 4; ++i) {
      const int col2 = (16 * w + 4 * g + i) * 2;
      *(unsigned short*)((char*)AsB + (c)      * 128 + (col2 ^ ((c & 7) << 4))) = f2b_(ac0[i]);
      *(unsigned short*)((char*)AsB + (c + 16) * 128 + (col2 ^ ((c & 7) << 4))) = f2b_(ac1[i]);
      *(unsigned short*)((char*)AsB + (c + 32) * 128 + (col2 ^ ((c & 7) << 4))) = f2b_(ac2[i]);
      *(unsigned short*)((char*)AsB + (c + 48) * 128 + (col2 ^ ((c & 7) << 4))) = f2b_(ac3[i]);
    }
    __syncthreads();
    const int hd = tid >> 2;
    const int tch = (tid & 3) << 4;
    const uint4 v0 = *(const uint4*)((const char*)AsB + hd * 128 + ((tch * 2) ^ ((hd & 7) << 4)));
    const uint4 v1 = *(const uint4*)((const char*)AsB + hd * 128 + ((tch * 2 + 16) ^ ((hd & 7) << 4)));
    unsigned short* dst = Vth + ((size_t)(bb2 * NH_ + h) * HD_ + hd) * T_ + tb + tch;
    *(uint4*)dst = v0;
    *(uint4*)(dst + 8) = v1;
  }

  // ---- threefry dropout-mask phase: ballot-packed ----
  const uint32 bid = (uint32)(blockIdx.y * 36 + blockIdx.x);
  const uint32 wvbeg = bid * 1408u + (uint32)w * 352u;
  for (uint32 wI = wvbeg; wI < wvbeg + 352u; wI += 4u) {
    const uint32 b0 = wI * 32u;
    const uint32 g0 = b0 + (uint32)lane;
    const uint32 g1 = g0 + 64u;
    uint32 thrS0, thrS1;
    {
      const uint32 row0 = b0 / 2112u;
      const uint32 cb0 = b0 - row0 * 2112u;
      thrS0 = ((row0 % 2112u) < 2048u && cb0 < 2048u) ? KXS_ : KLQS_;
      const uint32 b1v = b0 + 64u;
      const uint32 row1 = b1v / 2112u;
      const uint32 cb1 = b1v - row1 * 2112u;
      thrS1 = ((row1 % 2112u) < 2048u && cb1 < 2048u) ? KXS_ : KLQS_;
    }
    const uint2 ya = threefry_(0u, g0);
    const uint2 yb = threefry_(0u, g1);
    const unsigned long long balA = __ballot((ya.x ^ ya.y) < thrS0);
    const unsigned long long balB = __ballot((yb.x ^ yb.y) < thrS1);
    if (lane == 0) {
      uint4 st;
      st.x = (uint32)balA; st.y = (uint32)(balA >> 32);
      st.z = (uint32)balB; st.w = (uint32)(balB >> 32);
      *(uint4*)(Mask + wI) = st;
    }
  }
}

// ---------- MFMA flash attention (64 q-rows, 4 waves), bf16 ctx out ----------
__global__ __launch_bounds__(256) void attn_kernel(
    const unsigned short* __restrict__ Qh, const unsigned short* __restrict__ Kh,
    const unsigned short* __restrict__ Vth, const uint32* __restrict__ Mask,
    unsigned short* __restrict__ ctx) {
  __shared__ unsigned short KsU[4096];
  __shared__ unsigned short VsU[4096];
  __shared__ unsigned short PsU[4 * 1152];
  const int tid = threadIdx.x;
  const int w = tid >> 6;
  const int lane = tid & 63;
  const int c = lane & 15;
  const int g = lane >> 4;
  const int q0 = blockIdx.x << 6;
  const int h = blockIdx.y;
  const int b = blockIdx.z;
  const size_t hbT = (size_t)(b * NH_ + h) * T_;
  const size_t vbase = (size_t)(b * NH_ + h) * HD_;

  bf16x8 aq0, aq1;
  {
    const unsigned short* qrow = Qh + (hbT + q0 + 16 * w + c) * HD_ + (g << 3);
    aq0 = *(const bf16x8*)(qrow);
    aq1 = *(const bf16x8*)(qrow + 32);
  }
  f32x4 ca0 = {0.f, 0.f, 0.f, 0.f}, ca1 = ca0, ca2 = ca0, ca3 = ca0;
  float lacc[4] = {0.f, 0.f, 0.f, 0.f};
  uint32 wb[4];
#pragma unroll
  for (int i = 0; i < 4; ++i)
    wb[i] = ((uint32)b * HALF_U +
             (uint32)(h * T_ + q0 + 16 * w + 4 * g + i) * (uint32)T_) >> 5;

  const int psE = w * 1152;
  const int psB = w * 2304;
  const int swz = (c & 7) << 4;

  for (int kt = 0; kt < T_; kt += 64) {
#pragma unroll
    for (int ii = 0; ii < 2; ++ii) {
      const int seg = tid + (ii << 8);
      const int srow = seg >> 3;
      const int sc = (seg & 7) << 3;
      const uint4 kv4 = *(const uint4*)(Kh + (hbT + kt + srow) * HD_ + sc);
      *(uint4*)((char*)KsU + srow * 128 + ((sc * 2) ^ ((srow & 7) << 4))) = kv4;
      const uint4 vv4 = *(const uint4*)(Vth + (vbase + srow) * T_ + kt + sc);
      *(uint4*)((char*)VsU + srow * 128 + ((sc * 2) ^ ((srow & 7) << 4))) = vv4;
    }
    __syncthreads();

    f32x4 sa0 = {0.f, 0.f, 0.f, 0.f}, sa1 = sa0, sa2 = sa0, sa3 = sa0;
#pragma unroll
    for (int s = 0; s < 2; ++s) {
      const int off = ((s << 6) | (g << 4)) ^ swz;
      const bf16x8 bk0 = *(const bf16x8*)((const char*)KsU + (c) * 128 + off);
      const bf16x8 bk1 = *(const bf16x8*)((const char*)KsU + (c + 16) * 128 + off);
      const bf16x8 bk2 = *(const bf16x8*)((const char*)KsU + (c + 32) * 128 + off);
      const bf16x8 bk3 = *(const bf16x8*)((const char*)KsU + (c + 48) * 128 + off);
      const bf16x8 aqs = s ? aq1 : aq0;
      sa0 = __builtin_amdgcn_mfma_f32_16x16x32_bf16(aqs, bk0, sa0, 0, 0, 0);
      sa1 = __builtin_amdgcn_mfma_f32_16x16x32_bf16(aqs, bk1, sa1, 0, 0, 0);
      sa2 = __builtin_amdgcn_mfma_f32_16x16x32_bf16(aqs, bk2, sa2, 0, 0, 0);
      sa3 = __builtin_amdgcn_mfma_f32_16x16x32_bf16(aqs, bk3, sa3, 0, 0, 0);
    }

    const uint32 ktw = (uint32)(kt >> 5);
#pragma unroll
    for (int n = 0; n < 4; ++n) {
      const f32x4 sv = (n == 0) ? sa0 : (n == 1) ? sa1 : (n == 2) ? sa2 : sa3;
      const int sh = ((n & 1) << 4) + c;
      const uint32 wOff = ktw + (n >> 1);
#pragma unroll
      for (int i = 0; i < 4; ++i) {
        const float pe = __expf(sv[i]);
        lacc[i] += pe;
        const uint32 word = Mask[wb[i] + wOff];
        PsU[psE + (4 * g + i) * 72 + 16 * n + c] =
            ((word >> sh) & 1u) ? f2b_(pe) : (unsigned short)0;
      }
    }
    __syncthreads();

    const bf16x8 ap0 = *(const bf16x8*)((const char*)PsU + psB + c * 144 + (g << 4));
    const bf16x8 ap1 = *(const bf16x8*)((const char*)PsU + psB + c * 144 + 64 + (g << 4));
#pragma unroll
    for (int s = 0; s < 2; ++s) {
      const int off = ((s << 6) | (g << 4)) ^ swz;
      const bf16x8 bv0 = *(const bf16x8*)((const char*)VsU + (c) * 128 + off);
      const bf16x8 bv1 = *(const bf16x8*)((const char*)VsU + (c + 16) * 128 + off);
      const bf16x8 bv2 = *(const bf16x8*)((const char*)VsU + (c + 32) * 128 + off);
      const bf16x8 bv3 = *(const bf16x8*)((const char*)VsU + (c + 48) * 128 + off);
      const bf16x8 aps = s ? ap1 : ap0;
      ca0 = __builtin_amdgcn_mfma_f32_16x16x32_bf16(aps, bv0, ca0, 0, 0, 0);
      ca1 = __builtin_amdgcn_mfma_f32_16x16x32_bf16(aps, bv1, ca1, 0, 0, 0);
      ca2 = __builtin_amdgcn_mfma_f32_16x16x32_bf16(aps, bv2, ca2, 0, 0, 0);
      ca3 = __builtin_amdgcn_mfma_f32_16x16x32_bf16(aps, bv3, ca3, 0, 0, 0);
    }
    __syncthreads();
  }

#pragma unroll
  for (int i = 0; i < 4; ++i) {
    float li = lacc[i];
    li += __shfl_xor(li, 1);
    li += __shfl_xor(li, 2);
    li += __shfl_xor(li, 4);
    li += __shfl_xor(li, 8);
    const float inv = SCALE_ / li;
    unsigned short* dst =
        ctx + (size_t)(b * T_ + q0 + 16 * w + 4 * g + i) * DOUT_ + (h << 6) + c;
    dst[0]  = f2b_(ca0[i] * inv);
    dst[16] = f2b_(ca1[i] * inv);
    dst[32] = f2b_(ca2[i] * inv);
    dst[48] = f2b_(ca3[i] * inv);
  }
}

// ---------- oproj: bf16 MFMA GEMM + bias (bf16 A input) ----------
__global__ __launch_bounds__(256) void oproj_kernel(
    const unsigned short* __restrict__ ctxm, const unsigned short* __restrict__ Wt,
    const float* __restrict__ bo, float* __restrict__ out) {
  __shared__ unsigned short AsB[4096];
  __shared__ unsigned short BsB[4096];
  const int tid = threadIdx.x;
  const int w = tid >> 6;
  const int lane = tid & 63;
  const int c = lane & 15;
  const int g = lane >> 4;
  const int m0 = blockIdx.x << 6;
  const int n0 = blockIdx.y << 6;
  const int ar = tid >> 2;
  const int kpart = (tid & 3) << 4;
  const unsigned short* arow = ctxm + (size_t)(m0 + ar) * DIN_;
  const unsigned short* brow = Wt + ((size_t)3 * DOUT_ + n0 + ar) * DIN_;
  const int wrA = ar * 128;
  const int swzS = (ar & 7) << 4;
  const int swzF = (c & 7) << 4;

  f32x4 ac0 = {0.f, 0.f, 0.f, 0.f}, ac1 = ac0, ac2 = ac0, ac3 = ac0;
  for (int k0 = 0; k0 < DIN_; k0 += 64) {
    const uint4 a01 = *(const uint4*)(arow + k0 + kpart);
    const uint4 a23 = *(const uint4*)(arow + k0 + kpart + 8);
    const uint4 b01 = *(const uint4*)(brow + k0 + kpart);
    const uint4 b23 = *(const uint4*)(brow + k0 + kpart + 8);
    __syncthreads();
    *(uint4*)((char*)AsB + wrA + ((kpart * 2) ^ swzS)) = a01;
    *(uint4*)((char*)AsB + wrA + ((kpart * 2 + 16) ^ swzS)) = a23;
    *(uint4*)((char*)BsB + wrA + ((kpart * 2) ^ swzS)) = b01;
    *(uint4*)((char*)BsB + wrA + ((kpart * 2 + 16) ^ swzS)) = b23;
    __syncthreads();
#pragma unroll
    for (int s = 0; s < 2; ++s) {
      const int off = ((s << 6) | (g << 4)) ^ swzF;
      const bf16x8 af = *(const bf16x8*)((const char*)AsB + (16 * w + c) * 128 + off);
      const bf16x8 b0 = *(const bf16x8*)((const char*)BsB + (c) * 128 + off);
      const bf16x8 b1 = *(const bf16x8*)((const char*)BsB + (c + 16) * 128 + off);
      const bf16x8 b2 = *(const bf16x8*)((const char*)BsB + (c + 32) * 128 + off);
      const bf16x8 b3 = *(const bf16x8*)((const char*)BsB + (c + 48) * 128 + off);
      ac0 = __builtin_amdgcn_mfma_f32_16x16x32_bf16(af, b0, ac0, 0, 0, 0);
      ac1 = __builtin_amdgcn_mfma_f32_16x16x32_bf16(af, b1, ac1, 0, 0, 0);
      ac2 = __builtin_amdgcn_mfma_f32_16x16x32_bf16(af, b2, ac2, 0, 0, 0);
      ac3 = __builtin_amdgcn_mfma_f32_16x16x32_bf16(af, b3, ac3, 0, 0, 0);
    }
  }
  const float bi0 = bo[n0 + c];
  const float bi1 = bo[n0 + 16 + c];
  const float bi2 = bo[n0 + 32 + c];
  const float bi3 = bo[n0 + 48 + c];
#pragma unroll
  for (int i = 0; i < 4; ++i) {
    float* dst = out + (size_t)(m0 + 16 * w + 4 * g + i) * DOUT_ + n0 + c;
    dst[0]  = ac0[i] + bi0;
    dst[16] = ac1[i] + bi1;
    dst[32] = ac2[i] + bi2;
    dst[48] = ac3[i] + bi3;
  }
}

extern "C" void kernel_launch(void* const* d_in, const int* in_sizes, int n_in,
                              void* d_out, int out_size, void* d_ws, size_t ws_size,
                              hipStream_t stream) {
  (void)in_sizes; (void)n_in; (void)out_size; (void)ws_size;
  const float* x  = (const float*)d_in[0];
  const float* lq = (const float*)d_in[1];
  const float* Wq = (const float*)d_in[2];
  const float* Wk = (const float*)d_in[3];
  const float* Wv = (const float*)d_in[4];
  const float* Wo = (const float*)d_in[5];
  const float* bo = (const float*)d_in[6];
  unsigned short* Qh  = (unsigned short*)d_ws;
  unsigned short* Kh  = Qh + QSZ_;
  unsigned short* Vth = Kh + QSZ_;
  unsigned short* Cb  = Vth + QSZ_;                        // bf16 ctx (6.49 MB)
  unsigned short* Xb  = Cb;                                // aliases Cb: dead before attn
  unsigned short* Wt  = (unsigned short*)((char*)d_ws + 32440320);  // 4.72 MB
  uint32* Mask = (uint32*)((char*)d_ws + 37158912);        // 13.38 MB -> ends 50.5 MB
  xconv_kernel<<<dim3(1584), dim3(256), 0, stream>>>(x, lq, Xb);
  prep_kernel<<<dim3(12, 12, 4), dim3(256), 0, stream>>>(Wq, Wk, Wv, Wo, Wt);
  qkv_kernel<<<dim3(36, 66), dim3(256), 0, stream>>>(Xb, Wt, Qh, Kh, Vth, Mask);
  attn_kernel<<<dim3(33, NH_, B_), dim3(256), 0, stream>>>(Qh, Kh, Vth, Mask, Cb);
  oproj_kernel<<<dim3(66, 12), dim3(256), 0, stream>>>(Cb, Wt, bo, (float*)d_out);
}

// Round 12
// 409.957 us; speedup vs baseline: 1.4591x; 1.1728x over previous
//
#include <hip/hip_runtime.h>
#include <stdint.h>

#define B_ 2
#define NX_ 2048
#define NLQ_ 64
#define T_ 2112
#define DIN_ 768
#define DOUT_ 768
#define NH_ 12
#define HD_ 64

#define QSZ_ ((size_t)3244032)   // B*NH*T*HD elements
#define HALF_U 53526528u         // NH*T*T (per-batch flat count)
#define SCALE_ ((float)(4460544.0 / (4194304.0 * 0.9 + 266240.0 * 0.8)))
// pre-shifted integer dropout thresholds: keep  <=>  (y.x^y.y) < thr<<9
#define KXS_ 3865470464u
#define KLQS_ 3435974144u

typedef __attribute__((ext_vector_type(8))) short bf16x8;
typedef __attribute__((ext_vector_type(4))) float f32x4;
typedef unsigned int uint32;

__device__ __forceinline__ uint32 rotl_(uint32 x, uint32 r) {
  return (x << r) | (x >> (32u - r));
}

// Threefry-2x32, 20 rounds, key=(0,42); jax partitionable 32-bit: out = y.x ^ y.y
__device__ __forceinline__ uint2 threefry_(uint32 x0, uint32 x1) {
  const uint32 ks0 = 0u, ks1 = 42u;
  const uint32 ks2 = 0x1BD11BDAu ^ ks0 ^ ks1;
  x0 += ks0; x1 += ks1;
#define TFR_(r) { x0 += x1; x1 = rotl_(x1, (r)); x1 ^= x0; }
  TFR_(13) TFR_(15) TFR_(26) TFR_(6)
  x0 += ks1; x1 += ks2 + 1u;
  TFR_(17) TFR_(29) TFR_(16) TFR_(24)
  x0 += ks2; x1 += ks0 + 2u;
  TFR_(13) TFR_(15) TFR_(26) TFR_(6)
  x0 += ks0; x1 += ks1 + 3u;
  TFR_(17) TFR_(29) TFR_(16) TFR_(24)
  x0 += ks1; x1 += ks2 + 4u;
  TFR_(13) TFR_(15) TFR_(26) TFR_(6)
  x0 += ks2; x1 += ks0 + 5u;
#undef TFR_
  return make_uint2(x0, x1);
}

__device__ __forceinline__ unsigned short f2b_(float f) {  // f32 -> bf16 RNE
  const uint32 u = __float_as_uint(f);
  return (unsigned short)((u + 0x7FFFu + ((u >> 16) & 1u)) >> 16);
}
__device__ __forceinline__ uint32 pack2_(float lo, float hi) {
  return (uint32)f2b_(lo) | ((uint32)f2b_(hi) << 16);
}

// ---------- xconv: [x; lq] f32 -> Xb bf16 [B*T][768] ----------
__global__ __launch_bounds__(256) void xconv_kernel(
    const float* __restrict__ xg, const float* __restrict__ lqg,
    unsigned short* __restrict__ Xb) {
  const uint32 f = (blockIdx.x * 256u + threadIdx.x) * 8u;
  const uint32 m = f / 768u;
  const uint32 col = f - m * 768u;
  const uint32 bb = (m >= (uint32)T_) ? 1u : 0u;
  const uint32 tt = m - bb * (uint32)T_;
  const float* src = (tt < NX_) ? (xg + ((size_t)bb * NX_ + tt) * DIN_ + col)
                                : (lqg + ((size_t)bb * NLQ_ + (tt - NX_)) * DIN_ + col);
  const float4 a = *(const float4*)(src);
  const float4 b = *(const float4*)(src + 4);
  uint4 o;
  o.x = pack2_(a.x, a.y); o.y = pack2_(a.z, a.w);
  o.z = pack2_(b.x, b.y); o.w = pack2_(b.z, b.w);
  *(uint4*)(Xb + f) = o;
}

// ---------- prep: Wt[mat][n][k] bf16 = transpose(W[k][n]) for q,k,v,o ----------
__global__ __launch_bounds__(256) void prep_kernel(
    const float* __restrict__ Wq, const float* __restrict__ Wk,
    const float* __restrict__ Wv, const float* __restrict__ Wo,
    unsigned short* __restrict__ Wt) {
  __shared__ float Tf[64][65];
  const int tid = threadIdx.x;
  const int k0 = blockIdx.x << 6;
  const int n0 = blockIdx.y << 6;
  const int mat = blockIdx.z;
  const float* Wm = (mat == 0) ? Wq : (mat == 1) ? Wk : (mat == 2) ? Wv : Wo;
  const int r = tid >> 2;
  const int cch = (tid & 3) << 4;
  const float* src = Wm + (size_t)(k0 + r) * DOUT_ + n0 + cch;
#pragma unroll
  for (int j = 0; j < 4; ++j) {
    const float4 v = *(const float4*)(src + 4 * j);
    Tf[r][cch + 4 * j + 0] = v.x; Tf[r][cch + 4 * j + 1] = v.y;
    Tf[r][cch + 4 * j + 2] = v.z; Tf[r][cch + 4 * j + 3] = v.w;
  }
  __syncthreads();
  float f[16];
#pragma unroll
  for (int j = 0; j < 16; ++j) f[j] = Tf[cch + j][r];
  uint4 o0, o1;
  o0.x = pack2_(f[0], f[1]);  o0.y = pack2_(f[2], f[3]);
  o0.z = pack2_(f[4], f[5]);  o0.w = pack2_(f[6], f[7]);
  o1.x = pack2_(f[8], f[9]);  o1.y = pack2_(f[10], f[11]);
  o1.z = pack2_(f[12], f[13]); o1.w = pack2_(f[14], f[15]);
  unsigned short* dst = Wt + ((size_t)mat * DOUT_ + n0 + r) * DIN_ + k0 + cch;
  *(uint4*)dst = o0;
  *(uint4*)(dst + 8) = o1;
}

// ---------- qkv: bf16 MFMA GEMM (Q*0.125, K, V-transposed) + threefry mask phase ----------
// grid (36, 66): x = wsel*12+h (A-tile reuse: 36 consecutive blocks share one m-tile)
__global__ __launch_bounds__(256) void qkv_kernel(
    const unsigned short* __restrict__ Xb, const unsigned short* __restrict__ Wt,
    unsigned short* __restrict__ Qh, unsigned short* __restrict__ Kh,
    unsigned short* __restrict__ Vth, uint32* __restrict__ Mask) {
  __shared__ unsigned short AsB[4096];   // [64 m][64 k] bf16, XOR-swizzled rows
  __shared__ unsigned short BsB[4096];   // [64 n][64 k] bf16 (=W^T tile)
  const int tid = threadIdx.x;
  const int w = tid >> 6;
  const int lane = tid & 63;
  const int c = lane & 15;
  const int g = lane >> 4;
  const int wsel = blockIdx.x / NH_;
  const int h = blockIdx.x % NH_;
  const int m0 = blockIdx.y << 6;

  const int ar = tid >> 2;
  const int kpart = (tid & 3) << 4;
  const unsigned short* arow = Xb + (size_t)(m0 + ar) * DIN_;
  const unsigned short* brow = Wt + ((size_t)wsel * DOUT_ + h * HD_ + ar) * DIN_;
  const int wrA = ar * 128;
  const int swzS = (ar & 7) << 4;
  const int swzF = (c & 7) << 4;

  f32x4 ac0 = {0.f, 0.f, 0.f, 0.f}, ac1 = ac0, ac2 = ac0, ac3 = ac0;

  for (int k0 = 0; k0 < DIN_; k0 += 64) {
    const uint4 a01 = *(const uint4*)(arow + k0 + kpart);
    const uint4 a23 = *(const uint4*)(arow + k0 + kpart + 8);
    const uint4 b01 = *(const uint4*)(brow + k0 + kpart);
    const uint4 b23 = *(const uint4*)(brow + k0 + kpart + 8);
    __syncthreads();
    *(uint4*)((char*)AsB + wrA + ((kpart * 2) ^ swzS)) = a01;
    *(uint4*)((char*)AsB + wrA + ((kpart * 2 + 16) ^ swzS)) = a23;
    *(uint4*)((char*)BsB + wrA + ((kpart * 2) ^ swzS)) = b01;
    *(uint4*)((char*)BsB + wrA + ((kpart * 2 + 16) ^ swzS)) = b23;
    __syncthreads();
#pragma unroll
    for (int s = 0; s < 2; ++s) {
      const int off = ((s << 6) | (g << 4)) ^ swzF;
      const bf16x8 af = *(const bf16x8*)((const char*)AsB + (16 * w + c) * 128 + off);
      const bf16x8 b0 = *(const bf16x8*)((const char*)BsB + (c) * 128 + off);
      const bf16x8 b1 = *(const bf16x8*)((const char*)BsB + (c + 16) * 128 + off);
      const bf16x8 b2 = *(const bf16x8*)((const char*)BsB + (c + 32) * 128 + off);
      const bf16x8 b3 = *(const bf16x8*)((const char*)BsB + (c + 48) * 128 + off);
      ac0 = __builtin_amdgcn_mfma_f32_16x16x32_bf16(af, b0, ac0, 0, 0, 0);
      ac1 = __builtin_amdgcn_mfma_f32_16x16x32_bf16(af, b1, ac1, 0, 0, 0);
      ac2 = __builtin_amdgcn_mfma_f32_16x16x32_bf16(af, b2, ac2, 0, 0, 0);
      ac3 = __builtin_amdgcn_mfma_f32_16x16x32_bf16(af, b3, ac3, 0, 0, 0);
    }
  }

  const int bb2 = m0 / T_;
  const int tb = m0 - bb2 * T_;
  const size_t rowBase = (size_t)(bb2 * NH_ + h) * T_;
  if (wsel == 0) {
#pragma unroll
    for (int i = 0; i < 4; ++i) {
      const size_t rr = (rowBase + tb + 16 * w + 4 * g + i) * HD_ + c;
      Qh[rr +  0] = f2b_(ac0[i] * 0.125f);
      Qh[rr + 16] = f2b_(ac1[i] * 0.125f);
      Qh[rr + 32] = f2b_(ac2[i] * 0.125f);
      Qh[rr + 48] = f2b_(ac3[i] * 0.125f);
    }
  } else if (wsel == 1) {
#pragma unroll
    for (int i = 0; i < 4; ++i) {
      const size_t rr = (rowBase + tb + 16 * w + 4 * g + i) * HD_ + c;
      Kh[rr +  0] = f2b_(ac0[i]);
      Kh[rr + 16] = f2b_(ac1[i]);
      Kh[rr + 32] = f2b_(ac2[i]);
      Kh[rr + 48] = f2b_(ac3[i]);
    }
  } else {
    __syncthreads();   // all frag reads done; reuse AsB as transpose buffer
#pragma unroll
    for (int i = 0; i < 4; ++i) {
      const int col2 = (16 * w + 4 * g + i) * 2;
      *(unsigned short*)((char*)AsB + (c)      * 128 + (col2 ^ ((c & 7) << 4))) = f2b_(ac0[i]);
      *(unsigned short*)((char*)AsB + (c + 16) * 128 + (col2 ^ ((c & 7) << 4))) = f2b_(ac1[i]);
      *(unsigned short*)((char*)AsB + (c + 32) * 128 + (col2 ^ ((c & 7) << 4))) = f2b_(ac2[i]);
      *(unsigned short*)((char*)AsB + (c + 48) * 128 + (col2 ^ ((c & 7) << 4))) = f2b_(ac3[i]);
    }
    __syncthreads();
    const int hd = tid >> 2;
    const int tch = (tid & 3) << 4;
    const uint4 v0 = *(const uint4*)((const char*)AsB + hd * 128 + ((tch * 2) ^ ((hd & 7) << 4)));
    const uint4 v1 = *(const uint4*)((const char*)AsB + hd * 128 + ((tch * 2 + 16) ^ ((hd & 7) << 4)));
    unsigned short* dst = Vth + ((size_t)(bb2 * NH_ + h) * HD_ + hd) * T_ + tb + tch;
    *(uint4*)dst = v0;
    *(uint4*)(dst + 8) = v1;
  }

  // ---- threefry dropout-mask phase: scalar per-word (32 independent chains/thread) ----
  const uint32 bid = (uint32)(blockIdx.y * 36 + blockIdx.x);
  const uint32 wbeg = bid * 1408u;
  for (uint32 wI = wbeg + (uint32)tid; wI < wbeg + 1408u; wI += 256u) {
    const uint32 row = wI / 66u;          // word row (66 words per 2112-el row)
    const uint32 jw  = wI - row * 66u;
    const uint32 iQ  = row % (uint32)T_;  // q index within (b,h)
    const uint32 thrS = (iQ < (uint32)NX_ && jw < 64u) ? KXS_ : KLQS_;
    const uint32 c0 = wI * 32u;           // global flat element base
    uint32 word = 0u;
#pragma unroll 8
    for (int k = 0; k < 32; ++k) {
      const uint2 y = threefry_(0u, c0 + (uint32)k);
      word |= ((y.x ^ y.y) < thrS ? 1u : 0u) << k;
    }
    Mask[wI] = word;
  }
}

// ---------- MFMA flash attention (64 q-rows, 4 waves), bf16 ctx out ----------
__global__ __launch_bounds__(256) void attn_kernel(
    const unsigned short* __restrict__ Qh, const unsigned short* __restrict__ Kh,
    const unsigned short* __restrict__ Vth, const uint32* __restrict__ Mask,
    unsigned short* __restrict__ ctx) {
  __shared__ unsigned short KsU[4096];
  __shared__ unsigned short VsU[4096];
  __shared__ unsigned short PsU[4 * 1152];
  const int tid = threadIdx.x;
  const int w = tid >> 6;
  const int lane = tid & 63;
  const int c = lane & 15;
  const int g = lane >> 4;
  const int q0 = blockIdx.x << 6;
  const int h = blockIdx.y;
  const int b = blockIdx.z;
  const size_t hbT = (size_t)(b * NH_ + h) * T_;
  const size_t vbase = (size_t)(b * NH_ + h) * HD_;

  bf16x8 aq0, aq1;
  {
    const unsigned short* qrow = Qh + (hbT + q0 + 16 * w + c) * HD_ + (g << 3);
    aq0 = *(const bf16x8*)(qrow);
    aq1 = *(const bf16x8*)(qrow + 32);
  }
  f32x4 ca0 = {0.f, 0.f, 0.f, 0.f}, ca1 = ca0, ca2 = ca0, ca3 = ca0;
  float lacc[4] = {0.f, 0.f, 0.f, 0.f};
  uint32 wb[4];
#pragma unroll
  for (int i = 0; i < 4; ++i)
    wb[i] = ((uint32)b * HALF_U +
             (uint32)(h * T_ + q0 + 16 * w + 4 * g + i) * (uint32)T_) >> 5;

  const int psE = w * 1152;
  const int psB = w * 2304;
  const int swz = (c & 7) << 4;

  for (int kt = 0; kt < T_; kt += 64) {
#pragma unroll
    for (int ii = 0; ii < 2; ++ii) {
      const int seg = tid + (ii << 8);
      const int srow = seg >> 3;
      const int sc = (seg & 7) << 3;
      const uint4 kv4 = *(const uint4*)(Kh + (hbT + kt + srow) * HD_ + sc);
      *(uint4*)((char*)KsU + srow * 128 + ((sc * 2) ^ ((srow & 7) << 4))) = kv4;
      const uint4 vv4 = *(const uint4*)(Vth + (vbase + srow) * T_ + kt + sc);
      *(uint4*)((char*)VsU + srow * 128 + ((sc * 2) ^ ((srow & 7) << 4))) = vv4;
    }
    __syncthreads();

    f32x4 sa0 = {0.f, 0.f, 0.f, 0.f}, sa1 = sa0, sa2 = sa0, sa3 = sa0;
#pragma unroll
    for (int s = 0; s < 2; ++s) {
      const int off = ((s << 6) | (g << 4)) ^ swz;
      const bf16x8 bk0 = *(const bf16x8*)((const char*)KsU + (c) * 128 + off);
      const bf16x8 bk1 = *(const bf16x8*)((const char*)KsU + (c + 16) * 128 + off);
      const bf16x8 bk2 = *(const bf16x8*)((const char*)KsU + (c + 32) * 128 + off);
      const bf16x8 bk3 = *(const bf16x8*)((const char*)KsU + (c + 48) * 128 + off);
      const bf16x8 aqs = s ? aq1 : aq0;
      sa0 = __builtin_amdgcn_mfma_f32_16x16x32_bf16(aqs, bk0, sa0, 0, 0, 0);
      sa1 = __builtin_amdgcn_mfma_f32_16x16x32_bf16(aqs, bk1, sa1, 0, 0, 0);
      sa2 = __builtin_amdgcn_mfma_f32_16x16x32_bf16(aqs, bk2, sa2, 0, 0, 0);
      sa3 = __builtin_amdgcn_mfma_f32_16x16x32_bf16(aqs, bk3, sa3, 0, 0, 0);
    }

    const uint32 ktw = (uint32)(kt >> 5);
#pragma unroll
    for (int n = 0; n < 4; ++n) {
      const f32x4 sv = (n == 0) ? sa0 : (n == 1) ? sa1 : (n == 2) ? sa2 : sa3;
      const int sh = ((n & 1) << 4) + c;
      const uint32 wOff = ktw + (n >> 1);
#pragma unroll
      for (int i = 0; i < 4; ++i) {
        const float pe = __expf(sv[i]);
        lacc[i] += pe;
        const uint32 word = Mask[wb[i] + wOff];
        PsU[psE + (4 * g + i) * 72 + 16 * n + c] =
            ((word >> sh) & 1u) ? f2b_(pe) : (unsigned short)0;
      }
    }
    __syncthreads();

    const bf16x8 ap0 = *(const bf16x8*)((const char*)PsU + psB + c * 144 + (g << 4));
    const bf16x8 ap1 = *(const bf16x8*)((const char*)PsU + psB + c * 144 + 64 + (g << 4));
#pragma unroll
    for (int s = 0; s < 2; ++s) {
      const int off = ((s << 6) | (g << 4)) ^ swz;
      const bf16x8 bv0 = *(const bf16x8*)((const char*)VsU + (c) * 128 + off);
      const bf16x8 bv1 = *(const bf16x8*)((const char*)VsU + (c + 16) * 128 + off);
      const bf16x8 bv2 = *(const bf16x8*)((const char*)VsU + (c + 32) * 128 + off);
      const bf16x8 bv3 = *(const bf16x8*)((const char*)VsU + (c + 48) * 128 + off);
      const bf16x8 aps = s ? ap1 : ap0;
      ca0 = __builtin_amdgcn_mfma_f32_16x16x32_bf16(aps, bv0, ca0, 0, 0, 0);
      ca1 = __builtin_amdgcn_mfma_f32_16x16x32_bf16(aps, bv1, ca1, 0, 0, 0);
      ca2 = __builtin_amdgcn_mfma_f32_16x16x32_bf16(aps, bv2, ca2, 0, 0, 0);
      ca3 = __builtin_amdgcn_mfma_f32_16x16x32_bf16(aps, bv3, ca3, 0, 0, 0);
    }
    __syncthreads();
  }

#pragma unroll
  for (int i = 0; i < 4; ++i) {
    float li = lacc[i];
    li += __shfl_xor(li, 1);
    li += __shfl_xor(li, 2);
    li += __shfl_xor(li, 4);
    li += __shfl_xor(li, 8);
    const float inv = SCALE_ / li;
    unsigned short* dst =
        ctx + (size_t)(b * T_ + q0 + 16 * w + 4 * g + i) * DOUT_ + (h << 6) + c;
    dst[0]  = f2b_(ca0[i] * inv);
    dst[16] = f2b_(ca1[i] * inv);
    dst[32] = f2b_(ca2[i] * inv);
    dst[48] = f2b_(ca3[i] * inv);
  }
}

// ---------- oproj: bf16 MFMA GEMM + bias (bf16 A input) ----------
__global__ __launch_bounds__(256) void oproj_kernel(
    const unsigned short* __restrict__ ctxm, const unsigned short* __restrict__ Wt,
    const float* __restrict__ bo, float* __restrict__ out) {
  __shared__ unsigned short AsB[4096];
  __shared__ unsigned short BsB[4096];
  const int tid = threadIdx.x;
  const int w = tid >> 6;
  const int lane = tid & 63;
  const int c = lane & 15;
  const int g = lane >> 4;
  const int m0 = blockIdx.x << 6;
  const int n0 = blockIdx.y << 6;
  const int ar = tid >> 2;
  const int kpart = (tid & 3) << 4;
  const unsigned short* arow = ctxm + (size_t)(m0 + ar) * DIN_;
  const unsigned short* brow = Wt + ((size_t)3 * DOUT_ + n0 + ar) * DIN_;
  const int wrA = ar * 128;
  const int swzS = (ar & 7) << 4;
  const int swzF = (c & 7) << 4;

  f32x4 ac0 = {0.f, 0.f, 0.f, 0.f}, ac1 = ac0, ac2 = ac0, ac3 = ac0;
  for (int k0 = 0; k0 < DIN_; k0 += 64) {
    const uint4 a01 = *(const uint4*)(arow + k0 + kpart);
    const uint4 a23 = *(const uint4*)(arow + k0 + kpart + 8);
    const uint4 b01 = *(const uint4*)(brow + k0 + kpart);
    const uint4 b23 = *(const uint4*)(brow + k0 + kpart + 8);
    __syncthreads();
    *(uint4*)((char*)AsB + wrA + ((kpart * 2) ^ swzS)) = a01;
    *(uint4*)((char*)AsB + wrA + ((kpart * 2 + 16) ^ swzS)) = a23;
    *(uint4*)((char*)BsB + wrA + ((kpart * 2) ^ swzS)) = b01;
    *(uint4*)((char*)BsB + wrA + ((kpart * 2 + 16) ^ swzS)) = b23;
    __syncthreads();
#pragma unroll
    for (int s = 0; s < 2; ++s) {
      const int off = ((s << 6) | (g << 4)) ^ swzF;
      const bf16x8 af = *(const bf16x8*)((const char*)AsB + (16 * w + c) * 128 + off);
      const bf16x8 b0 = *(const bf16x8*)((const char*)BsB + (c) * 128 + off);
      const bf16x8 b1 = *(const bf16x8*)((const char*)BsB + (c + 16) * 128 + off);
      const bf16x8 b2 = *(const bf16x8*)((const char*)BsB + (c + 32) * 128 + off);
      const bf16x8 b3 = *(const bf16x8*)((const char*)BsB + (c + 48) * 128 + off);
      ac0 = __builtin_amdgcn_mfma_f32_16x16x32_bf16(af, b0, ac0, 0, 0, 0);
      ac1 = __builtin_amdgcn_mfma_f32_16x16x32_bf16(af, b1, ac1, 0, 0, 0);
      ac2 = __builtin_amdgcn_mfma_f32_16x16x32_bf16(af, b2, ac2, 0, 0, 0);
      ac3 = __builtin_amdgcn_mfma_f32_16x16x32_bf16(af, b3, ac3, 0, 0, 0);
    }
  }
  const float bi0 = bo[n0 + c];
  const float bi1 = bo[n0 + 16 + c];
  const float bi2 = bo[n0 + 32 + c];
  const float bi3 = bo[n0 + 48 + c];
#pragma unroll
  for (int i = 0; i < 4; ++i) {
    float* dst = out + (size_t)(m0 + 16 * w + 4 * g + i) * DOUT_ + n0 + c;
    dst[0]  = ac0[i] + bi0;
    dst[16] = ac1[i] + bi1;
    dst[32] = ac2[i] + bi2;
    dst[48] = ac3[i] + bi3;
  }
}

extern "C" void kernel_launch(void* const* d_in, const int* in_sizes, int n_in,
                              void* d_out, int out_size, void* d_ws, size_t ws_size,
                              hipStream_t stream) {
  (void)in_sizes; (void)n_in; (void)out_size; (void)ws_size;
  const float* x  = (const float*)d_in[0];
  const float* lq = (const float*)d_in[1];
  const float* Wq = (const float*)d_in[2];
  const float* Wk = (const float*)d_in[3];
  const float* Wv = (const float*)d_in[4];
  const float* Wo = (const float*)d_in[5];
  const float* bo = (const float*)d_in[6];
  unsigned short* Qh  = (unsigned short*)d_ws;
  unsigned short* Kh  = Qh + QSZ_;
  unsigned short* Vth = Kh + QSZ_;
  unsigned short* Cb  = Vth + QSZ_;                        // bf16 ctx (6.49 MB)
  unsigned short* Xb  = Cb;                                // aliases Cb: dead before attn
  unsigned short* Wt  = (unsigned short*)((char*)d_ws + 32440320);  // 4.72 MB
  uint32* Mask = (uint32*)((char*)d_ws + 37158912);        // 13.38 MB -> ends 50.5 MB
  xconv_kernel<<<dim3(1584), dim3(256), 0, stream>>>(x, lq, Xb);
  prep_kernel<<<dim3(12, 12, 4), dim3(256), 0, stream>>>(Wq, Wk, Wv, Wo, Wt);
  qkv_kernel<<<dim3(36, 66), dim3(256), 0, stream>>>(Xb, Wt, Qh, Kh, Vth, Mask);
  attn_kernel<<<dim3(33, NH_, B_), dim3(256), 0, stream>>>(Qh, Kh, Vth, Mask, Cb);
  oproj_kernel<<<dim3(66, 12), dim3(256), 0, stream>>>(Cb, Wt, bo, (float*)d_out);
}

// Round 14
// 402.558 us; speedup vs baseline: 1.4859x; 1.0184x over previous
//
#include <hip/hip_runtime.h>
#include <stdint.h>

#define B_ 2
#define NX_ 2048
#define NLQ_ 64
#define T_ 2112
#define DIN_ 768
#define DOUT_ 768
#define NH_ 12
#define HD_ 64

#define QSZ_ ((size_t)3244032)   // B*NH*T*HD elements
#define HALF_U 53526528u         // NH*T*T (per-batch flat count)
#define SCALE_ ((float)(4460544.0 / (4194304.0 * 0.9 + 266240.0 * 0.8)))
// pre-shifted integer dropout thresholds: keep  <=>  (y.x^y.y) < thr<<9
#define KXS_ 3865470464u
#define KLQS_ 3435974144u

typedef __attribute__((ext_vector_type(8))) short bf16x8;
typedef __attribute__((ext_vector_type(4))) float f32x4;
typedef unsigned int uint32;

__device__ __forceinline__ uint32 rotl_(uint32 x, uint32 r) {
  return (x << r) | (x >> (32u - r));
}

// Threefry-2x32, 20 rounds, key=(0,42); jax partitionable 32-bit: out = y.x ^ y.y
__device__ __forceinline__ uint2 threefry_(uint32 x0, uint32 x1) {
  const uint32 ks0 = 0u, ks1 = 42u;
  const uint32 ks2 = 0x1BD11BDAu ^ ks0 ^ ks1;
  x0 += ks0; x1 += ks1;
#define TFR_(r) { x0 += x1; x1 = rotl_(x1, (r)); x1 ^= x0; }
  TFR_(13) TFR_(15) TFR_(26) TFR_(6)
  x0 += ks1; x1 += ks2 + 1u;
  TFR_(17) TFR_(29) TFR_(16) TFR_(24)
  x0 += ks2; x1 += ks0 + 2u;
  TFR_(13) TFR_(15) TFR_(26) TFR_(6)
  x0 += ks0; x1 += ks1 + 3u;
  TFR_(17) TFR_(29) TFR_(16) TFR_(24)
  x0 += ks1; x1 += ks2 + 4u;
  TFR_(13) TFR_(15) TFR_(26) TFR_(6)
  x0 += ks2; x1 += ks0 + 5u;
#undef TFR_
  return make_uint2(x0, x1);
}

__device__ __forceinline__ unsigned short f2b_(float f) {  // f32 -> bf16 RNE
  const uint32 u = __float_as_uint(f);
  return (unsigned short)((u + 0x7FFFu + ((u >> 16) & 1u)) >> 16);
}
__device__ __forceinline__ uint32 pack2_(float lo, float hi) {
  return (uint32)f2b_(lo) | ((uint32)f2b_(hi) << 16);
}

// ---------- xconv: [x; lq] f32 -> Xb bf16 [B*T][768] ----------
__global__ __launch_bounds__(256) void xconv_kernel(
    const float* __restrict__ xg, const float* __restrict__ lqg,
    unsigned short* __restrict__ Xb) {
  const uint32 f = (blockIdx.x * 256u + threadIdx.x) * 8u;
  const uint32 m = f / 768u;
  const uint32 col = f - m * 768u;
  const uint32 bb = (m >= (uint32)T_) ? 1u : 0u;
  const uint32 tt = m - bb * (uint32)T_;
  const float* src = (tt < NX_) ? (xg + ((size_t)bb * NX_ + tt) * DIN_ + col)
                                : (lqg + ((size_t)bb * NLQ_ + (tt - NX_)) * DIN_ + col);
  const float4 a = *(const float4*)(src);
  const float4 b = *(const float4*)(src + 4);
  uint4 o;
  o.x = pack2_(a.x, a.y); o.y = pack2_(a.z, a.w);
  o.z = pack2_(b.x, b.y); o.w = pack2_(b.z, b.w);
  *(uint4*)(Xb + f) = o;
}

// ---------- prep: Wt[mat][n][k] bf16 = transpose(W[k][n]) for q,k,v,o ----------
__global__ __launch_bounds__(256) void prep_kernel(
    const float* __restrict__ Wq, const float* __restrict__ Wk,
    const float* __restrict__ Wv, const float* __restrict__ Wo,
    unsigned short* __restrict__ Wt) {
  __shared__ float Tf[64][65];
  const int tid = threadIdx.x;
  const int k0 = blockIdx.x << 6;
  const int n0 = blockIdx.y << 6;
  const int mat = blockIdx.z;
  const float* Wm = (mat == 0) ? Wq : (mat == 1) ? Wk : (mat == 2) ? Wv : Wo;
  const int r = tid >> 2;
  const int cch = (tid & 3) << 4;
  const float* src = Wm + (size_t)(k0 + r) * DOUT_ + n0 + cch;
#pragma unroll
  for (int j = 0; j < 4; ++j) {
    const float4 v = *(const float4*)(src + 4 * j);
    Tf[r][cch + 4 * j + 0] = v.x; Tf[r][cch + 4 * j + 1] = v.y;
    Tf[r][cch + 4 * j + 2] = v.z; Tf[r][cch + 4 * j + 3] = v.w;
  }
  __syncthreads();
  float f[16];
#pragma unroll
  for (int j = 0; j < 16; ++j) f[j] = Tf[cch + j][r];
  uint4 o0, o1;
  o0.x = pack2_(f[0], f[1]);  o0.y = pack2_(f[2], f[3]);
  o0.z = pack2_(f[4], f[5]);  o0.w = pack2_(f[6], f[7]);
  o1.x = pack2_(f[8], f[9]);  o1.y = pack2_(f[10], f[11]);
  o1.z = pack2_(f[12], f[13]); o1.w = pack2_(f[14], f[15]);
  unsigned short* dst = Wt + ((size_t)mat * DOUT_ + n0 + r) * DIN_ + k0 + cch;
  *(uint4*)dst = o0;
  *(uint4*)(dst + 8) = o1;
}

// ---------- qkv: bf16 MFMA GEMM (dbuf + async-stage) + threefry mask phase ----------
// grid (36, 66): x = wsel*12+h
__global__ __launch_bounds__(256) void qkv_kernel(
    const unsigned short* __restrict__ Xb, const unsigned short* __restrict__ Wt,
    unsigned short* __restrict__ Qh, unsigned short* __restrict__ Kh,
    unsigned short* __restrict__ Vth, uint32* __restrict__ Mask) {
  __shared__ unsigned short AsB[2][4096];   // [64 m][64 k] bf16, XOR-swizzled, dbuf
  __shared__ unsigned short BsB[2][4096];   // [64 n][64 k] bf16 (=W^T tile), dbuf
  const int tid = threadIdx.x;
  const int w = tid >> 6;
  const int lane = tid & 63;
  const int c = lane & 15;
  const int g = lane >> 4;
  const int wsel = blockIdx.x / NH_;
  const int h = blockIdx.x % NH_;
  const int m0 = blockIdx.y << 6;

  const int ar = tid >> 2;
  const int kpart = (tid & 3) << 4;
  const unsigned short* arow = Xb + (size_t)(m0 + ar) * DIN_;
  const unsigned short* brow = Wt + ((size_t)wsel * DOUT_ + h * HD_ + ar) * DIN_;
  const int wrA = ar * 128;
  const int swzS = (ar & 7) << 4;
  const int swzF = (c & 7) << 4;

  // prologue: stage k-tile 0 into buffer 0
  {
    const uint4 a01 = *(const uint4*)(arow + kpart);
    const uint4 a23 = *(const uint4*)(arow + kpart + 8);
    const uint4 b01 = *(const uint4*)(brow + kpart);
    const uint4 b23 = *(const uint4*)(brow + kpart + 8);
    *(uint4*)((char*)AsB[0] + wrA + ((kpart * 2) ^ swzS)) = a01;
    *(uint4*)((char*)AsB[0] + wrA + ((kpart * 2 + 16) ^ swzS)) = a23;
    *(uint4*)((char*)BsB[0] + wrA + ((kpart * 2) ^ swzS)) = b01;
    *(uint4*)((char*)BsB[0] + wrA + ((kpart * 2 + 16) ^ swzS)) = b23;
  }

  f32x4 ac0 = {0.f, 0.f, 0.f, 0.f}, ac1 = ac0, ac2 = ac0, ac3 = ac0;

  for (int kt = 0; kt < 12; ++kt) {
    const int cur = kt & 1;
    uint4 na01, na23, nb01, nb23;
    if (kt < 11) {                      // issue next tile's loads early (T14)
      const int k0 = (kt + 1) << 6;
      na01 = *(const uint4*)(arow + k0 + kpart);
      na23 = *(const uint4*)(arow + k0 + kpart + 8);
      nb01 = *(const uint4*)(brow + k0 + kpart);
      nb23 = *(const uint4*)(brow + k0 + kpart + 8);
    }
    __syncthreads();                    // buf[cur] writes from prev iter visible
#pragma unroll
    for (int s = 0; s < 2; ++s) {
      const int off = ((s << 6) | (g << 4)) ^ swzF;
      const bf16x8 af = *(const bf16x8*)((const char*)AsB[cur] + (16 * w + c) * 128 + off);
      const bf16x8 b0 = *(const bf16x8*)((const char*)BsB[cur] + (c) * 128 + off);
      const bf16x8 b1 = *(const bf16x8*)((const char*)BsB[cur] + (c + 16) * 128 + off);
      const bf16x8 b2 = *(const bf16x8*)((const char*)BsB[cur] + (c + 32) * 128 + off);
      const bf16x8 b3 = *(const bf16x8*)((const char*)BsB[cur] + (c + 48) * 128 + off);
      ac0 = __builtin_amdgcn_mfma_f32_16x16x32_bf16(af, b0, ac0, 0, 0, 0);
      ac1 = __builtin_amdgcn_mfma_f32_16x16x32_bf16(af, b1, ac1, 0, 0, 0);
      ac2 = __builtin_amdgcn_mfma_f32_16x16x32_bf16(af, b2, ac2, 0, 0, 0);
      ac3 = __builtin_amdgcn_mfma_f32_16x16x32_bf16(af, b3, ac3, 0, 0, 0);
    }
    if (kt < 11) {                      // write-late into alternate buffer
      const int nxt = cur ^ 1;
      *(uint4*)((char*)AsB[nxt] + wrA + ((kpart * 2) ^ swzS)) = na01;
      *(uint4*)((char*)AsB[nxt] + wrA + ((kpart * 2 + 16) ^ swzS)) = na23;
      *(uint4*)((char*)BsB[nxt] + wrA + ((kpart * 2) ^ swzS)) = nb01;
      *(uint4*)((char*)BsB[nxt] + wrA + ((kpart * 2 + 16) ^ swzS)) = nb23;
    }
  }

  const int bb2 = m0 / T_;
  const int tb = m0 - bb2 * T_;
  const size_t rowBase = (size_t)(bb2 * NH_ + h) * T_;
  if (wsel == 0) {
#pragma unroll
    for (int i = 0; i < 4; ++i) {
      const size_t rr = (rowBase + tb + 16 * w + 4 * g + i) * HD_ + c;
      Qh[rr +  0] = f2b_(ac0[i] * 0.125f);
      Qh[rr + 16] = f2b_(ac1[i] * 0.125f);
      Qh[rr + 32] = f2b_(ac2[i] * 0.125f);
      Qh[rr + 48] = f2b_(ac3[i] * 0.125f);
    }
  } else if (wsel == 1) {
#pragma unroll
    for (int i = 0; i < 4; ++i) {
      const size_t rr = (rowBase + tb + 16 * w + 4 * g + i) * HD_ + c;
      Kh[rr +  0] = f2b_(ac0[i]);
      Kh[rr + 16] = f2b_(ac1[i]);
      Kh[rr + 32] = f2b_(ac2[i]);
      Kh[rr + 48] = f2b_(ac3[i]);
    }
  } else {
    // V: transpose through AsB[0] (last read of buf0 was iter 10; safe after sync(11))
#pragma unroll
    for (int i = 0; i < 4; ++i) {
      const int col2 = (16 * w + 4 * g + i) * 2;
      *(unsigned short*)((char*)AsB[0] + (c)      * 128 + (col2 ^ ((c & 7) << 4))) = f2b_(ac0[i]);
      *(unsigned short*)((char*)AsB[0] + (c + 16) * 128 + (col2 ^ ((c & 7) << 4))) = f2b_(ac1[i]);
      *(unsigned short*)((char*)AsB[0] + (c + 32) * 128 + (col2 ^ ((c & 7) << 4))) = f2b_(ac2[i]);
      *(unsigned short*)((char*)AsB[0] + (c + 48) * 128 + (col2 ^ ((c & 7) << 4))) = f2b_(ac3[i]);
    }
    __syncthreads();
    const int hd = tid >> 2;
    const int tch = (tid & 3) << 4;
    const uint4 v0 = *(const uint4*)((const char*)AsB[0] + hd * 128 + ((tch * 2) ^ ((hd & 7) << 4)));
    const uint4 v1 = *(const uint4*)((const char*)AsB[0] + hd * 128 + ((tch * 2 + 16) ^ ((hd & 7) << 4)));
    unsigned short* dst = Vth + ((size_t)(bb2 * NH_ + h) * HD_ + hd) * T_ + tb + tch;
    *(uint4*)dst = v0;
    *(uint4*)(dst + 8) = v1;
  }

  // ---- threefry dropout-mask phase: scalar per-word (32 independent chains/thread) ----
  const uint32 bid = (uint32)(blockIdx.y * 36 + blockIdx.x);
  const uint32 wbeg = bid * 1408u;
  for (uint32 wI = wbeg + (uint32)tid; wI < wbeg + 1408u; wI += 256u) {
    const uint32 row = wI / 66u;          // word row (66 words per 2112-el row)
    const uint32 jw  = wI - row * 66u;
    const uint32 iQ  = row % (uint32)T_;  // q index within (b,h)
    const uint32 thrS = (iQ < (uint32)NX_ && jw < 64u) ? KXS_ : KLQS_;
    const uint32 c0 = wI * 32u;           // global flat element base
    uint32 word = 0u;
#pragma unroll 8
    for (int k = 0; k < 32; ++k) {
      const uint2 y = threefry_(0u, c0 + (uint32)k);
      word |= ((y.x ^ y.y) < thrS ? 1u : 0u) << k;
    }
    Mask[wI] = word;
  }
}

// ---------- MFMA flash attention (64 q-rows, 4 waves), dbuf K/V + async-stage ----------
__global__ __launch_bounds__(256) void attn_kernel(
    const unsigned short* __restrict__ Qh, const unsigned short* __restrict__ Kh,
    const unsigned short* __restrict__ Vth, const uint32* __restrict__ Mask,
    unsigned short* __restrict__ ctx) {
  __shared__ unsigned short KsU[2][4096];
  __shared__ unsigned short VsU[2][4096];
  __shared__ unsigned short PsU[4 * 1152];
  const int tid = threadIdx.x;
  const int w = tid >> 6;
  const int lane = tid & 63;
  const int c = lane & 15;
  const int g = lane >> 4;
  const int q0 = blockIdx.x << 6;
  const int h = blockIdx.y;
  const int b = blockIdx.z;
  const size_t hbT = (size_t)(b * NH_ + h) * T_;
  const size_t vbase = (size_t)(b * NH_ + h) * HD_;

  bf16x8 aq0, aq1;
  {
    const unsigned short* qrow = Qh + (hbT + q0 + 16 * w + c) * HD_ + (g << 3);
    aq0 = *(const bf16x8*)(qrow);
    aq1 = *(const bf16x8*)(qrow + 32);
  }
  f32x4 ca0 = {0.f, 0.f, 0.f, 0.f}, ca1 = ca0, ca2 = ca0, ca3 = ca0;
  float lacc[4] = {0.f, 0.f, 0.f, 0.f};
  uint32 wb[4];
#pragma unroll
  for (int i = 0; i < 4; ++i)
    wb[i] = ((uint32)b * HALF_U +
             (uint32)(h * T_ + q0 + 16 * w + 4 * g + i) * (uint32)T_) >> 5;

  const int psE = w * 1152;
  const int psB = w * 2304;
  const int swz = (c & 7) << 4;
  const int srow0 = tid >> 3;
  const int sc0 = (tid & 7) << 3;
  const int srow1 = (tid + 256) >> 3;
  const int sc1 = ((tid + 256) & 7) << 3;

  // prologue: stage kv-tile 0 into buffer 0
  {
    *(uint4*)((char*)KsU[0] + srow0 * 128 + ((sc0 * 2) ^ ((srow0 & 7) << 4))) =
        *(const uint4*)(Kh + (hbT + srow0) * HD_ + sc0);
    *(uint4*)((char*)VsU[0] + srow0 * 128 + ((sc0 * 2) ^ ((srow0 & 7) << 4))) =
        *(const uint4*)(Vth + (vbase + srow0) * T_ + sc0);
    *(uint4*)((char*)KsU[0] + srow1 * 128 + ((sc1 * 2) ^ ((srow1 & 7) << 4))) =
        *(const uint4*)(Kh + (hbT + srow1) * HD_ + sc1);
    *(uint4*)((char*)VsU[0] + srow1 * 128 + ((sc1 * 2) ^ ((srow1 & 7) << 4))) =
        *(const uint4*)(Vth + (vbase + srow1) * T_ + sc1);
  }

  for (int t = 0; t < 33; ++t) {
    const int cur = t & 1;
    const int kt = t << 6;
    uint4 nk0, nv0, nk1, nv1;
    if (t < 32) {                       // issue next tile's loads early (T14)
      const int ktn = kt + 64;
      nk0 = *(const uint4*)(Kh + (hbT + ktn + srow0) * HD_ + sc0);
      nv0 = *(const uint4*)(Vth + (vbase + srow0) * T_ + ktn + sc0);
      nk1 = *(const uint4*)(Kh + (hbT + ktn + srow1) * HD_ + sc1);
      nv1 = *(const uint4*)(Vth + (vbase + srow1) * T_ + ktn + sc1);
    }
    __syncthreads();                    // buf[cur] ready

    f32x4 sa0 = {0.f, 0.f, 0.f, 0.f}, sa1 = sa0, sa2 = sa0, sa3 = sa0;
#pragma unroll
    for (int s = 0; s < 2; ++s) {
      const int off = ((s << 6) | (g << 4)) ^ swz;
      const bf16x8 bk0 = *(const bf16x8*)((const char*)KsU[cur] + (c) * 128 + off);
      const bf16x8 bk1 = *(const bf16x8*)((const char*)KsU[cur] + (c + 16) * 128 + off);
      const bf16x8 bk2 = *(const bf16x8*)((const char*)KsU[cur] + (c + 32) * 128 + off);
      const bf16x8 bk3 = *(const bf16x8*)((const char*)KsU[cur] + (c + 48) * 128 + off);
      const bf16x8 aqs = s ? aq1 : aq0;
      sa0 = __builtin_amdgcn_mfma_f32_16x16x32_bf16(aqs, bk0, sa0, 0, 0, 0);
      sa1 = __builtin_amdgcn_mfma_f32_16x16x32_bf16(aqs, bk1, sa1, 0, 0, 0);
      sa2 = __builtin_amdgcn_mfma_f32_16x16x32_bf16(aqs, bk2, sa2, 0, 0, 0);
      sa3 = __builtin_amdgcn_mfma_f32_16x16x32_bf16(aqs, bk3, sa3, 0, 0, 0);
    }

    const uint32 ktw = (uint32)(kt >> 5);
#pragma unroll
    for (int n = 0; n < 4; ++n) {
      const f32x4 sv = (n == 0) ? sa0 : (n == 1) ? sa1 : (n == 2) ? sa2 : sa3;
      const int sh = ((n & 1) << 4) + c;
      const uint32 wOff = ktw + (n >> 1);
#pragma unroll
      for (int i = 0; i < 4; ++i) {
        const float pe = __expf(sv[i]);
        lacc[i] += pe;
        const uint32 word = Mask[wb[i] + wOff];
        PsU[psE + (4 * g + i) * 72 + 16 * n + c] =
            ((word >> sh) & 1u) ? f2b_(pe) : (unsigned short)0;
      }
    }
    // Ps is per-wave: wave-local LDS ordering suffices (no block barrier)
    asm volatile("s_waitcnt lgkmcnt(0)" ::: "memory");

    const bf16x8 ap0 = *(const bf16x8*)((const char*)PsU + psB + c * 144 + (g << 4));
    const bf16x8 ap1 = *(const bf16x8*)((const char*)PsU + psB + c * 144 + 64 + (g << 4));
#pragma unroll
    for (int s = 0; s < 2; ++s) {
      const int off = ((s << 6) | (g << 4)) ^ swz;
      const bf16x8 bv0 = *(const bf16x8*)((const char*)VsU[cur] + (c) * 128 + off);
      const bf16x8 bv1 = *(const bf16x8*)((const char*)VsU[cur] + (c + 16) * 128 + off);
      const bf16x8 bv2 = *(const bf16x8*)((const char*)VsU[cur] + (c + 32) * 128 + off);
      const bf16x8 bv3 = *(const bf16x8*)((const char*)VsU[cur] + (c + 48) * 128 + off);
      const bf16x8 aps = s ? ap1 : ap0;
      ca0 = __builtin_amdgcn_mfma_f32_16x16x32_bf16(aps, bv0, ca0, 0, 0, 0);
      ca1 = __builtin_amdgcn_mfma_f32_16x16x32_bf16(aps, bv1, ca1, 0, 0, 0);
      ca2 = __builtin_amdgcn_mfma_f32_16x16x32_bf16(aps, bv2, ca2, 0, 0, 0);
      ca3 = __builtin_amdgcn_mfma_f32_16x16x32_bf16(aps, bv3, ca3, 0, 0, 0);
    }

    if (t < 32) {                       // write-late into alternate buffer
      const int nxt = cur ^ 1;
      *(uint4*)((char*)KsU[nxt] + srow0 * 128 + ((sc0 * 2) ^ ((srow0 & 7) << 4))) = nk0;
      *(uint4*)((char*)VsU[nxt] + srow0 * 128 + ((sc0 * 2) ^ ((srow0 & 7) << 4))) = nv0;
      *(uint4*)((char*)KsU[nxt] + srow1 * 128 + ((sc1 * 2) ^ ((srow1 & 7) << 4))) = nk1;
      *(uint4*)((char*)VsU[nxt] + srow1 * 128 + ((sc1 * 2) ^ ((srow1 & 7) << 4))) = nv1;
    }
  }

#pragma unroll
  for (int i = 0; i < 4; ++i) {
    float li = lacc[i];
    li += __shfl_xor(li, 1);
    li += __shfl_xor(li, 2);
    li += __shfl_xor(li, 4);
    li += __shfl_xor(li, 8);
    const float inv = SCALE_ / li;
    unsigned short* dst =
        ctx + (size_t)(b * T_ + q0 + 16 * w + 4 * g + i) * DOUT_ + (h << 6) + c;
    dst[0]  = f2b_(ca0[i] * inv);
    dst[16] = f2b_(ca1[i] * inv);
    dst[32] = f2b_(ca2[i] * inv);
    dst[48] = f2b_(ca3[i] * inv);
  }
}

// ---------- oproj: bf16 MFMA GEMM + bias (bf16 A input) ----------
__global__ __launch_bounds__(256) void oproj_kernel(
    const unsigned short* __restrict__ ctxm, const unsigned short* __restrict__ Wt,
    const float* __restrict__ bo, float* __restrict__ out) {
  __shared__ unsigned short AsB[4096];
  __shared__ unsigned short BsB[4096];
  const int tid = threadIdx.x;
  const int w = tid >> 6;
  const int lane = tid & 63;
  const int c = lane & 15;
  const int g = lane >> 4;
  const int m0 = blockIdx.x << 6;
  const int n0 = blockIdx.y << 6;
  const int ar = tid >> 2;
  const int kpart = (tid & 3) << 4;
  const unsigned short* arow = ctxm + (size_t)(m0 + ar) * DIN_;
  const unsigned short* brow = Wt + ((size_t)3 * DOUT_ + n0 + ar) * DIN_;
  const int wrA = ar * 128;
  const int swzS = (ar & 7) << 4;
  const int swzF = (c & 7) << 4;

  f32x4 ac0 = {0.f, 0.f, 0.f, 0.f}, ac1 = ac0, ac2 = ac0, ac3 = ac0;
  for (int k0 = 0; k0 < DIN_; k0 += 64) {
    const uint4 a01 = *(const uint4*)(arow + k0 + kpart);
    const uint4 a23 = *(const uint4*)(arow + k0 + kpart + 8);
    const uint4 b01 = *(const uint4*)(brow + k0 + kpart);
    const uint4 b23 = *(const uint4*)(brow + k0 + kpart + 8);
    __syncthreads();
    *(uint4*)((char*)AsB + wrA + ((kpart * 2) ^ swzS)) = a01;
    *(uint4*)((char*)AsB + wrA + ((kpart * 2 + 16) ^ swzS)) = a23;
    *(uint4*)((char*)BsB + wrA + ((kpart * 2) ^ swzS)) = b01;
    *(uint4*)((char*)BsB + wrA + ((kpart * 2 + 16) ^ swzS)) = b23;
    __syncthreads();
#pragma unroll
    for (int s = 0; s < 2; ++s) {
      const int off = ((s << 6) | (g << 4)) ^ swzF;
      const bf16x8 af = *(const bf16x8*)((const char*)AsB + (16 * w + c) * 128 + off);
      const bf16x8 b0 = *(const bf16x8*)((const char*)BsB + (c) * 128 + off);
      const bf16x8 b1 = *(const bf16x8*)((const char*)BsB + (c + 16) * 128 + off);
      const bf16x8 b2 = *(const bf16x8*)((const char*)BsB + (c + 32) * 128 + off);
      const bf16x8 b3 = *(const bf16x8*)((const char*)BsB + (c + 48) * 128 + off);
      ac0 = __builtin_amdgcn_mfma_f32_16x16x32_bf16(af, b0, ac0, 0, 0, 0);
      ac1 = __builtin_amdgcn_mfma_f32_16x16x32_bf16(af, b1, ac1, 0, 0, 0);
      ac2 = __builtin_amdgcn_mfma_f32_16x16x32_bf16(af, b2, ac2, 0, 0, 0);
      ac3 = __builtin_amdgcn_mfma_f32_16x16x32_bf16(af, b3, ac3, 0, 0, 0);
    }
  }
  const float bi0 = bo[n0 + c];
  const float bi1 = bo[n0 + 16 + c];
  const float bi2 = bo[n0 + 32 + c];
  const float bi3 = bo[n0 + 48 + c];
#pragma unroll
  for (int i = 0; i < 4; ++i) {
    float* dst = out + (size_t)(m0 + 16 * w + 4 * g + i) * DOUT_ + n0 + c;
    dst[0]  = ac0[i] + bi0;
    dst[16] = ac1[i] + bi1;
    dst[32] = ac2[i] + bi2;
    dst[48] = ac3[i] + bi3;
  }
}

extern "C" void kernel_launch(void* const* d_in, const int* in_sizes, int n_in,
                              void* d_out, int out_size, void* d_ws, size_t ws_size,
                              hipStream_t stream) {
  (void)in_sizes; (void)n_in; (void)out_size; (void)ws_size;
  const float* x  = (const float*)d_in[0];
  const float* lq = (const float*)d_in[1];
  const float* Wq = (const float*)d_in[2];
  const float* Wk = (const float*)d_in[3];
  const float* Wv = (const float*)d_in[4];
  const float* Wo = (const float*)d_in[5];
  const float* bo = (const float*)d_in[6];
  unsigned short* Qh  = (unsigned short*)d_ws;
  unsigned short* Kh  = Qh + QSZ_;
  unsigned short* Vth = Kh + QSZ_;
  unsigned short* Cb  = Vth + QSZ_;                        // bf16 ctx (6.49 MB)
  unsigned short* Xb  = Cb;                                // aliases Cb: dead before attn
  unsigned short* Wt  = (unsigned short*)((char*)d_ws + 32440320);  // 4.72 MB
  uint32* Mask = (uint32*)((char*)d_ws + 37158912);        // 13.38 MB -> ends 50.5 MB
  xconv_kernel<<<dim3(1584), dim3(256), 0, stream>>>(x, lq, Xb);
  prep_kernel<<<dim3(12, 12, 4), dim3(256), 0, stream>>>(Wq, Wk, Wv, Wo, Wt);
  qkv_kernel<<<dim3(36, 66), dim3(256), 0, stream>>>(Xb, Wt, Qh, Kh, Vth, Mask);
  attn_kernel<<<dim3(33, NH_, B_), dim3(256), 0, stream>>>(Qh, Kh, Vth, Mask, Cb);
  oproj_kernel<<<dim3(66, 12), dim3(256), 0, stream>>>(Cb, Wt, bo, (float*)d_out);
}